// Round 5
// baseline (947.511 us; speedup 1.0000x reference)
//
#include <hip/hip_runtime.h>
#include <hip/hip_bf16.h>
#include <math.h>
#include <stdint.h>

#define NN 10000
#define EE 100000
#define DD 768
#define HH 4
#define CC 192
#define EDIM 16
#define NREL 10
#define MP 10112           // NN padded to multiple of 128 for GEMM tiles
#define NQKV 3072          // fused output width: [q|k|v|skip]
#define SCALE 0.07216878364870322f   // 1/sqrt(192)

using short8  = __attribute__((ext_vector_type(8))) short;
using floatx4 = __attribute__((ext_vector_type(4))) float;

// ---------------- helpers ----------------

__device__ __forceinline__ float b2f(short u) {
    union { unsigned int i; float f; } t;
    t.i = ((unsigned int)(unsigned short)u) << 16;
    return t.f;
}

__device__ __forceinline__ short f2b(float f) {
    __hip_bfloat16 h = __float2bfloat16(f);
    short r;
    __builtin_memcpy(&r, &h, 2);
    return r;
}

__device__ __forceinline__ __hip_bfloat16 rd_any(const void* p, long long j, int bf) {
    if (bf) return ((const __hip_bfloat16*)p)[j];
    return __float2bfloat16(((const float*)p)[j]);
}

// async global->LDS, 16B per lane; LDS dest must be wave-uniform base + lane*16
__device__ __forceinline__ void gload16(const __hip_bfloat16* g, __hip_bfloat16* l) {
    __builtin_amdgcn_global_load_lds(
        (const __attribute__((address_space(1))) unsigned int*)g,
        (__attribute__((address_space(3))) unsigned int*)l, 16, 0, 0);
}

// ---------------- dtype detection ----------------
__global__ void detect_kernel(const void* edge_attr, int* flag) {
    const unsigned short* p = (const unsigned short*)edge_attr;
    int t = threadIdx.x;
    int nz = (p[4 * t] != 0) ? 1 : 0;
    unsigned long long m = __ballot(nz);
    if (t == 0) *flag = (__popcll(m) > 8) ? 1 : 0;
}

// ---------------- input conversion ----------------

__global__ __launch_bounds__(256) void cvt_big(
    const void* x, const void* We, const int* flag,
    __hip_bfloat16* hb, __hip_bfloat16* Web) {
    long long i = (long long)blockIdx.x * 256 + threadIdx.x;
    int bf = *flag;
    const long long NX = (long long)NN * DD;
    const long long NE2 = 3LL * EDIM * DD;
    if (i < NX) { hb[i] = rd_any(x, i, bf); return; } i -= NX;
    if (i < NE2) { Web[i] = rd_any(We, i, bf); return; } i -= NE2;
    if (i < (long long)(MP - NN) * DD) hb[(long long)NN * DD + i] = __float2bfloat16(0.0f);
}

__global__ __launch_bounds__(256) void cvt_small(
    const void* ea, const void* rel, const void* Wed, const void* bed,
    const void* bk, const void* bq, const void* bv, const void* bs,
    const void* lg, const void* lb, const int* flag,
    __hip_bfloat16* eab, __hip_bfloat16* relb, __hip_bfloat16* Wedb,
    __hip_bfloat16* bedb, __hip_bfloat16* ballb, __hip_bfloat16* lgb,
    __hip_bfloat16* lbb) {
    long long i = (long long)blockIdx.x * 256 + threadIdx.x;
    int bf = *flag;
    if (i < 2LL * EE) { eab[i] = rd_any(ea, i, bf); return; } i -= 2LL * EE;
    if (i < NREL * (EDIM - 1)) { relb[i] = rd_any(rel, i, bf); return; } i -= NREL * (EDIM - 1);
    if (i < EDIM * EDIM) { Wedb[i] = rd_any(Wed, i, bf); return; } i -= EDIM * EDIM;
    if (i < EDIM) { bedb[i] = rd_any(bed, i, bf); return; } i -= EDIM;
    if (i < 3 * NQKV) {
        int l = (int)(i / NQKV), c = (int)(i % NQKV);
        const void* src; long long off;
        if (c < 768)       { src = bq; off = (long long)l * DD + c; }
        else if (c < 1536) { src = bk; off = (long long)l * DD + (c - 768); }
        else if (c < 2304) { src = bv; off = (long long)l * DD + (c - 1536); }
        else               { src = bs; off = (long long)l * DD + (c - 2304); }
        ballb[i] = rd_any(src, off, bf); return;
    } i -= 3 * NQKV;
    if (i < DD) { lgb[i] = rd_any(lg, i, bf); return; } i -= DD;
    if (i < DD) { lbb[i] = rd_any(lb, i, bf); return; }
}

// all-layer fused transposed weights: Wt3[l][n][k], n: [q|k|v|skip]
__global__ __launch_bounds__(256) void wt_all(
    const void* Wq, const void* Wk, const void* Wv, const void* Ws,
    const int* flag, __hip_bfloat16* Wt3) {
    __shared__ __hip_bfloat16 tile[32][33];
    int mm = blockIdx.y;            // l*4 + m
    int l = mm >> 2, m = mm & 3;
    const void* src = (m == 0) ? Wq : (m == 1) ? Wk : (m == 2) ? Wv : Ws;
    int bx = blockIdx.x;            // 24*24 tiles of 32x32
    int tr = bx / 24, tc = bx % 24;
    int k0 = tr * 32, c0 = tc * 32;
    int t = threadIdx.x;
    int rr = t >> 5, cc = t & 31;
    int bf = *flag;
    long long base = (long long)l * DD * DD;
#pragma unroll
    for (int p = 0; p < 4; p++)
        tile[p * 8 + rr][cc] =
            rd_any(src, base + (long long)(k0 + p * 8 + rr) * DD + c0 + cc, bf);
    __syncthreads();
    __hip_bfloat16* dst = Wt3 + (size_t)l * NQKV * DD + (size_t)(m * 768 + c0) * DD + k0;
#pragma unroll
    for (int p = 0; p < 4; p++)
        dst[(size_t)(p * 8 + rr) * DD + cc] = tile[cc][p * 8 + rr];
}

// ---------------- CSR build (incoming edges per dst) ----------------

__global__ __launch_bounds__(256) void zero_counts(int* counts) {
    int i = blockIdx.x * 256 + threadIdx.x;
    if (i < NN) counts[i] = 0;
}

__global__ __launch_bounds__(256) void count_kernel(const int* ei, int* counts) {
    int e = blockIdx.x * 256 + threadIdx.x;
    if (e < EE) atomicAdd(&counts[ei[EE + e]], 1);
}

__global__ __launch_bounds__(256) void scan_kernel(const int* counts, int* rowptr) {
    __shared__ int sdata[256];
    int t = threadIdx.x;
    int base = t * 40;
    int cnt = (base < NN) ? min(40, NN - base) : 0;
    int s = 0;
    for (int i = 0; i < cnt; i++) s += counts[base + i];
    sdata[t] = s;
    __syncthreads();
    for (int off = 1; off < 256; off <<= 1) {
        int add = (t >= off) ? sdata[t - off] : 0;
        __syncthreads();
        sdata[t] += add;
        __syncthreads();
    }
    int run = sdata[t] - s;  // exclusive prefix
    for (int i = 0; i < cnt; i++) {
        run += counts[base + i];
        rowptr[base + i + 1] = run;
    }
    if (t == 0) rowptr[0] = 0;
}

__global__ __launch_bounds__(256) void cursor_kernel(const int* rowptr, int* cursor) {
    int i = blockIdx.x * 256 + threadIdx.x;
    if (i < NN) cursor[i] = rowptr[i];
}

__global__ __launch_bounds__(256) void fill_kernel(const int* ei, int* cursor,
                                                   int* eids, int* esrc) {
    int e = blockIdx.x * 256 + threadIdx.x;
    if (e < EE) {
        int d = ei[EE + e];
        int pos = atomicAdd(&cursor[d], 1);
        eids[pos] = e;
        esrc[pos] = ei[e];
    }
}

// ---------------- edge features (CSR-ordered: ef[p] for CSR slot p) ----------------

__global__ __launch_bounds__(256) void ef_kernel(
    const int* __restrict__ eids,
    const __hip_bfloat16* __restrict__ eab, const __hip_bfloat16* __restrict__ relb,
    const __hip_bfloat16* __restrict__ Wedb, const __hip_bfloat16* __restrict__ bedb,
    float* __restrict__ ef) {
    int idx = blockIdx.x * 256 + threadIdx.x;
    if (idx >= EE * EDIM) return;
    int p = idx >> 4, j = idx & 15;
    int e = eids[p];
    int rid = (int)((float)eab[e * 2 + 0]);
    rid = min(max(rid, 0), NREL - 1);
    float w = (float)eab[e * 2 + 1];
    float s = (float)bedb[j];
#pragma unroll
    for (int i = 0; i < 15; i++)
        s += (float)relb[rid * 15 + i] * (float)Wedb[i * EDIM + j];
    s += w * (float)Wedb[15 * EDIM + j];
    ef[idx] = s;
}

// ---------------- fused GEMM: C[NN,3072] = A[MP,768] @ Wt[3072,768]^T + bias ----
// 128x128 tile, BK=32, async width-16 staging, XOR bank swizzle,
// padded-stride LDS-bounce epilogue (conflict-free staging).

__global__ __launch_bounds__(256) void gemm_fused(
    const __hip_bfloat16* __restrict__ A, const __hip_bfloat16* __restrict__ Bt,
    const __hip_bfloat16* __restrict__ bias, __hip_bfloat16* __restrict__ C) {
    __shared__ __hip_bfloat16 As[128 * 32];   // 8 KB
    __shared__ __hip_bfloat16 Bs[128 * 32];   // 8 KB
    __shared__ __hip_bfloat16 stg[32 * 132];  // 8.25 KB, padded stride 132
    const int tid  = threadIdx.x;
    const int wid  = tid >> 6, lane = tid & 63;
    const int quad = lane >> 4, l15 = lane & 15;
    const int m0 = blockIdx.y * 128, n0 = blockIdx.x * 128;
    const int wm = wid >> 1, wn = wid & 1;
    floatx4 acc[4][4] = {};
    for (int k0 = 0; k0 < DD; k0 += 32) {
#pragma unroll
        for (int j = 0; j < 2; j++) {
            int c = j * 256 + tid;            // chunk index, 16B each
            int r = c >> 2, s = c & 3;
            int ks = s ^ ((r + (r >> 2)) & 3);   // source k-chunk (XOR swizzle)
            gload16(A + (size_t)(m0 + r) * DD + k0 + ks * 8, As + c * 8);
            gload16(Bt + (size_t)(n0 + r) * DD + k0 + ks * 8, Bs + c * 8);
        }
        __syncthreads();
        short8 a[4], b[4];
#pragma unroll
        for (int mt = 0; mt < 4; mt++) {
            int R = wm * 64 + mt * 16 + l15;
            int sw = quad ^ ((R + (R >> 2)) & 3);
            a[mt] = *(const short8*)(As + R * 32 + sw * 8);
        }
#pragma unroll
        for (int nt = 0; nt < 4; nt++) {
            int R = wn * 64 + nt * 16 + l15;
            int sw = quad ^ ((R + (R >> 2)) & 3);
            b[nt] = *(const short8*)(Bs + R * 32 + sw * 8);
        }
#pragma unroll
        for (int mt = 0; mt < 4; mt++)
#pragma unroll
            for (int nt = 0; nt < 4; nt++)
                acc[mt][nt] = __builtin_amdgcn_mfma_f32_16x16x32_bf16(a[mt], b[nt], acc[mt][nt], 0, 0, 0);
        __syncthreads();
    }
    // epilogue: per mt, stage 32 rows (wm*16+quad*4+r) x 128 cols, stride 132
    float bv[4];
#pragma unroll
    for (int nt = 0; nt < 4; nt++) bv[nt] = (float)bias[n0 + wn * 64 + nt * 16 + l15];
    const int rr = tid >> 3, ccs = (tid & 7) * 16;
    const int grow = m0 + (rr >> 4) * 64 + (rr & 15);
    for (int mt = 0; mt < 4; mt++) {
#pragma unroll
        for (int nt = 0; nt < 4; nt++) {
            int col = wn * 64 + nt * 16 + l15;
#pragma unroll
            for (int r = 0; r < 4; r++) {
                int lr = wm * 16 + quad * 4 + r;
                stg[lr * 132 + col] = __float2bfloat16(acc[mt][nt][r] + bv[nt]);
            }
        }
        __syncthreads();
        int row = grow + mt * 16;
        if (row < NN) {
            const short8* sp = (const short8*)(stg + rr * 132 + ccs);
            short8 v0 = sp[0], v1 = sp[1];
            short8* dp = (short8*)(C + (size_t)row * NQKV + n0 + ccs);
            dp[0] = v0; dp[1] = v1;
        }
        __syncthreads();
    }
}

// ---------------- attention ----------------
// qkvs row layout: [q(0) | k(768) | v(1536) | skip(2304)]

// Qe[n,h,j] = dot(q[n, h*C:(h+1)*C], We_l[j, h*C:(h+1)*C])
__global__ __launch_bounds__(256) void qe_kernel(
    const __hip_bfloat16* __restrict__ qkvs, const __hip_bfloat16* __restrict__ Wel,
    float* __restrict__ Qe) {
    int idx = blockIdx.x * 256 + threadIdx.x;
    if (idx >= NN * HH * EDIM) return;
    int n = idx >> 6, hj = idx & 63, hh = hj >> 4, j = hj & 15;
    const __hip_bfloat16* qrow = qkvs + (size_t)n * NQKV + hh * CC;
    const __hip_bfloat16* wrow = Wel + (size_t)j * DD + hh * CC;
    float s = 0.f;
    for (int c = 0; c < CC; c++) s += (float)qrow[c] * (float)wrow[c];
    Qe[idx] = s;
}

// persistent waves: wave handles nodes w, w+2048, ... Fused alpha + online
// softmax + gather + S@We + skip + gelu. Lane owns channels [lane*12, +12).
__global__ __launch_bounds__(256) void node_attn(
    const int* __restrict__ rowptr, const int* __restrict__ esrc,
    const __hip_bfloat16* __restrict__ qkvs, const float* __restrict__ Qe,
    const float* __restrict__ ef, const __hip_bfloat16* __restrict__ Wel,
    __hip_bfloat16* __restrict__ hb, int do_gelu) {
    const int wid = threadIdx.x >> 6, lane = threadIdx.x & 63;
    const int w0 = blockIdx.x * 4 + wid;    // wave id, 512*4 = 2048 waves
    const int sj = lane & 15;
    const int hbase = lane & 48;            // head*16
    for (int n = w0; n < NN; n += 2048) {
        const int s0 = rowptr[n], s1 = rowptr[n + 1];
        float q[12];
        {
            const short4* qp = (const short4*)(qkvs + (size_t)n * NQKV + lane * 12);
            short4 a = qp[0], b = qp[1], c = qp[2];
            q[0] = b2f(a.x); q[1] = b2f(a.y); q[2]  = b2f(a.z); q[3]  = b2f(a.w);
            q[4] = b2f(b.x); q[5] = b2f(b.y); q[6]  = b2f(b.z); q[7]  = b2f(b.w);
            q[8] = b2f(c.x); q[9] = b2f(c.y); q[10] = b2f(c.z); q[11] = b2f(c.w);
        }
        float qe_l = Qe[n * 64 + lane];
        float m = -INFINITY, lsum = 0.f, sacc = 0.f;
        float acc[12];
#pragma unroll
        for (int i = 0; i < 12; i++) acc[i] = 0.f;
        for (int p = s0; p < s1; p++) {
            int src = esrc[p];
            const short4* kp = (const short4*)(qkvs + (size_t)src * NQKV + 768 + lane * 12);
            const short4* vp = (const short4*)(qkvs + (size_t)src * NQKV + 1536 + lane * 12);
            short4 ka = kp[0], kb = kp[1], kc = kp[2];
            short4 va = vp[0], vb = vp[1], vc = vp[2];
            float efv = ef[(size_t)p * 16 + sj];
            float kv[12], vv[12];
            kv[0] = b2f(ka.x); kv[1] = b2f(ka.y); kv[2]  = b2f(ka.z); kv[3]  = b2f(ka.w);
            kv[4] = b2f(kb.x); kv[5] = b2f(kb.y); kv[6]  = b2f(kb.z); kv[7]  = b2f(kb.w);
            kv[8] = b2f(kc.x); kv[9] = b2f(kc.y); kv[10] = b2f(kc.z); kv[11] = b2f(kc.w);
            vv[0] = b2f(va.x); vv[1] = b2f(va.y); vv[2]  = b2f(va.z); vv[3]  = b2f(va.w);
            vv[4] = b2f(vb.x); vv[5] = b2f(vb.y); vv[6]  = b2f(vb.z); vv[7]  = b2f(vb.w);
            vv[8] = b2f(vc.x); vv[9] = b2f(vc.y); vv[10] = b2f(vc.z); vv[11] = b2f(vc.w);
            float part = qe_l * efv;
#pragma unroll
            for (int i = 0; i < 12; i++) part += q[i] * kv[i];
            part += __shfl_xor(part, 1); part += __shfl_xor(part, 2);
            part += __shfl_xor(part, 4); part += __shfl_xor(part, 8);
            float a = part * SCALE;
            float nm = fmaxf(m, a);
            float sc = __expf(m - nm);
            float w  = __expf(a - nm);
            lsum = lsum * sc + w;
            m = nm;
#pragma unroll
            for (int i = 0; i < 12; i++) acc[i] = acc[i] * sc + w * vv[i];
            sacc = sacc * sc + w * efv;
        }
        float inv = 1.0f / (lsum + 1e-16f);
#pragma unroll
        for (int i = 0; i < 12; i++) acc[i] *= inv;
        float sS = sacc * inv;
        // skip connection
        {
            const short4* sp = (const short4*)(qkvs + (size_t)n * NQKV + 2304 + lane * 12);
            short4 a = sp[0], b = sp[1], c = sp[2];
            acc[0] += b2f(a.x); acc[1] += b2f(a.y); acc[2]  += b2f(a.z); acc[3]  += b2f(a.w);
            acc[4] += b2f(b.x); acc[5] += b2f(b.y); acc[6]  += b2f(b.z); acc[7]  += b2f(b.w);
            acc[8] += b2f(c.x); acc[9] += b2f(c.y); acc[10] += b2f(c.z); acc[11] += b2f(c.w);
        }
        // + S @ We (per-head 16-dim): S[h][j] broadcast via shfl
#pragma unroll
        for (int j = 0; j < 16; j++) {
            float sv = __shfl(sS, hbase + j);
            const short4* wp = (const short4*)(Wel + (size_t)j * DD + lane * 12);
            short4 a = wp[0], b = wp[1], c = wp[2];
            acc[0] += sv * b2f(a.x); acc[1] += sv * b2f(a.y);
            acc[2] += sv * b2f(a.z); acc[3] += sv * b2f(a.w);
            acc[4] += sv * b2f(b.x); acc[5] += sv * b2f(b.y);
            acc[6] += sv * b2f(b.z); acc[7] += sv * b2f(b.w);
            acc[8] += sv * b2f(c.x); acc[9] += sv * b2f(c.y);
            acc[10] += sv * b2f(c.z); acc[11] += sv * b2f(c.w);
        }
        if (do_gelu) {
#pragma unroll
            for (int i = 0; i < 12; i++)
                acc[i] = 0.5f * acc[i] * (1.0f + erff(acc[i] * 0.70710678118654752f));
        }
        short4 o0, o1, o2;
        o0.x = f2b(acc[0]); o0.y = f2b(acc[1]); o0.z = f2b(acc[2]); o0.w = f2b(acc[3]);
        o1.x = f2b(acc[4]); o1.y = f2b(acc[5]); o1.z = f2b(acc[6]); o1.w = f2b(acc[7]);
        o2.x = f2b(acc[8]); o2.y = f2b(acc[9]); o2.z = f2b(acc[10]); o2.w = f2b(acc[11]);
        short4* hp = (short4*)(hb + (size_t)n * DD + lane * 12);
        hp[0] = o0; hp[1] = o1; hp[2] = o2;
    }
}

// ---------------- LN + mean pool ----------------

__global__ __launch_bounds__(256) void ln_pool(
    const __hip_bfloat16* __restrict__ hb, const __hip_bfloat16* __restrict__ g,
    const __hip_bfloat16* __restrict__ b, float* __restrict__ partial) {
    __shared__ float sbuf[4][768];
    int grp = blockIdx.x, t = threadIdx.x;
    int wid = t >> 6, lane = t & 63;
    float gv[12], bv[12], acc[12];
#pragma unroll
    for (int i = 0; i < 12; i++) {
        gv[i] = (float)g[lane + i * 64];
        bv[i] = (float)b[lane + i * 64];
        acc[i] = 0.f;
    }
    for (int r = wid; r < 25; r += 4) {
        const __hip_bfloat16* row = hb + (size_t)(grp * 25 + r) * DD;
        float x[12];
        float s = 0.f, q = 0.f;
#pragma unroll
        for (int i = 0; i < 12; i++) {
            x[i] = (float)row[lane + i * 64];
            s += x[i]; q += x[i] * x[i];
        }
#pragma unroll
        for (int m = 32; m > 0; m >>= 1) {
            s += __shfl_xor(s, m); q += __shfl_xor(q, m);
        }
        float mu = s * (1.0f / 768.0f);
        float ms = q * (1.0f / 768.0f);
        float inv = 1.0f / sqrtf(ms - mu * mu + 1e-5f);
#pragma unroll
        for (int i = 0; i < 12; i++)
            acc[i] += (x[i] - mu) * inv * gv[i] + bv[i];
    }
#pragma unroll
    for (int i = 0; i < 12; i++) sbuf[wid][lane + i * 64] = acc[i];
    __syncthreads();
#pragma unroll
    for (int j = 0; j < 3; j++) {
        int col = t + j * 256;
        partial[(size_t)grp * DD + col] =
            sbuf[0][col] + sbuf[1][col] + sbuf[2][col] + sbuf[3][col];
    }
}

__global__ __launch_bounds__(256) void pool1_kernel(
    const float* __restrict__ partial, float* __restrict__ partial2) {
    int idx = blockIdx.x * 256 + threadIdx.x;     // 16*768
    if (idx >= 16 * DD) return;
    int g2 = idx / DD, col = idx % DD;
    float s = 0.f;
    for (int r = 0; r < 25; r++) s += partial[(size_t)(g2 * 25 + r) * DD + col];
    partial2[idx] = s;
}

__global__ __launch_bounds__(256) void pool2_kernel(
    const float* __restrict__ partial2, void* __restrict__ out,
    const int* __restrict__ flag) {
    int dd = blockIdx.x * 256 + threadIdx.x;
    if (dd >= DD) return;
    float s = 0.f;
#pragma unroll
    for (int g2 = 0; g2 < 16; g2++) s += partial2[g2 * DD + dd];
    s *= (1.0f / 10000.0f);
    if (*flag) ((__hip_bfloat16*)out)[dd] = __float2bfloat16(s);
    else ((float*)out)[dd] = s;
}

// ---------------- launch ----------------

extern "C" void kernel_launch(void* const* d_in, const int* in_sizes, int n_in,
                              void* d_out, int out_size, void* d_ws, size_t ws_size,
                              hipStream_t stream) {
    const void* x         = d_in[0];
    const void* edge_attr = d_in[1];
    const int*  ei        = (const int*)d_in[2];
    const void* rel_emb   = d_in[3];
    const void* W_edge    = d_in[4];
    const void* b_edge    = d_in[5];
    const void* Wk        = d_in[6];
    const void* bk        = d_in[7];
    const void* Wq        = d_in[8];
    const void* bq        = d_in[9];
    const void* Wv        = d_in[10];
    const void* bv        = d_in[11];
    const void* We        = d_in[12];
    const void* Wskip     = d_in[13];
    const void* bskip     = d_in[14];
    const void* ln_g      = d_in[15];
    const void* ln_b      = d_in[16];

    char* ws = (char*)d_ws;
    // ---- workspace layout (~102.8 MB total) ----
    int*   flag    = (int*)(ws + 0);
    int*   counts  = (int*)(ws + 256);          // 40,000
    int*   rowptr  = (int*)(ws + 40448);        // 40,004
    int*   cursor  = (int*)(ws + 80640);        // 40,000
    int*   eids    = (int*)(ws + 120832);       // 400,000
    int*   esrc    = (int*)(ws + 520960);       // 400,000
    float* ef      = (float*)(ws + 920960);     // 6,400,000 (CSR-ordered)
    float* Qe      = (float*)(ws + 7320960);    // 2,560,000
    float* partial = (float*)(ws + 9880960);    // 1,228,800
    float* partial2= (float*)(ws + 11109760);   // 49,152
    __hip_bfloat16* eab   = (__hip_bfloat16*)(ws + 11158912);  // 400,000
    __hip_bfloat16* relb  = (__hip_bfloat16*)(ws + 11559296);  // 300
    __hip_bfloat16* Wedb  = (__hip_bfloat16*)(ws + 11559680);  // 512
    __hip_bfloat16* bedb  = (__hip_bfloat16*)(ws + 11560192);  // 32
    __hip_bfloat16* ballb = (__hip_bfloat16*)(ws + 11560320);  // 18,432
    __hip_bfloat16* lngb  = (__hip_bfloat16*)(ws + 11578752);  // 1,536
    __hip_bfloat16* lnbb  = (__hip_bfloat16*)(ws + 11580288);  // 1,536
    __hip_bfloat16* Web   = (__hip_bfloat16*)(ws + 11581824);  // 73,728
    __hip_bfloat16* hb    = (__hip_bfloat16*)(ws + 11655552);  // 15,532,032 (MP*768)
    __hip_bfloat16* Wt3   = (__hip_bfloat16*)(ws + 27187584);  // 14,155,776
    __hip_bfloat16* qkvs  = (__hip_bfloat16*)(ws + 41343360);  // 61,440,000 -> 102,783,360

    dim3 blk(256);

    detect_kernel<<<dim3(1), dim3(64), 0, stream>>>(edge_attr, flag);

    {
        long long tot = (long long)NN * DD + 3LL * EDIM * DD + (long long)(MP - NN) * DD;
        cvt_big<<<dim3((unsigned)((tot + 255) / 256)), blk, 0, stream>>>(x, We, flag, hb, Web);
    }
    {
        long long tot = 2LL * EE + NREL * (EDIM - 1) + EDIM * EDIM + EDIM
                        + 3LL * NQKV + 2LL * DD;
        cvt_small<<<dim3((unsigned)((tot + 255) / 256)), blk, 0, stream>>>(
            edge_attr, rel_emb, W_edge, b_edge, bk, bq, bv, bskip, ln_g, ln_b,
            flag, eab, relb, Wedb, bedb, ballb, lngb, lnbb);
    }
    wt_all<<<dim3(576, 12), blk, 0, stream>>>(Wq, Wk, Wv, Wskip, flag, Wt3);

    // CSR build
    zero_counts<<<dim3(40), blk, 0, stream>>>(counts);
    count_kernel<<<dim3((EE + 255) / 256), blk, 0, stream>>>(ei, counts);
    scan_kernel<<<dim3(1), blk, 0, stream>>>(counts, rowptr);
    cursor_kernel<<<dim3(40), blk, 0, stream>>>(rowptr, cursor);
    fill_kernel<<<dim3((EE + 255) / 256), blk, 0, stream>>>(ei, cursor, eids, esrc);

    ef_kernel<<<dim3((EE * EDIM) / 256), blk, 0, stream>>>(eids, eab, relb, Wedb, bedb, ef);

    for (int l = 0; l < 3; l++) {
        const __hip_bfloat16* We_l = Web + (size_t)l * EDIM * DD;
        gemm_fused<<<dim3(NQKV / 128, MP / 128), blk, 0, stream>>>(
            hb, Wt3 + (size_t)l * NQKV * DD, ballb + (size_t)l * NQKV, qkvs);
        qe_kernel<<<dim3((NN * 64) / 256), blk, 0, stream>>>(qkvs, We_l, Qe);
        node_attn<<<dim3(512), blk, 0, stream>>>(rowptr, esrc, qkvs, Qe, ef,
                                                 We_l, hb, (l < 2) ? 1 : 0);
    }

    ln_pool<<<dim3(400), blk, 0, stream>>>(hb, lngb, lnbb, partial);
    pool1_kernel<<<dim3(48), blk, 0, stream>>>(partial, partial2);
    pool2_kernel<<<dim3(3), blk, 0, stream>>>(partial2, d_out, flag);
}

// Round 6
// 759.495 us; speedup vs baseline: 1.2476x; 1.2476x over previous
//
#include <hip/hip_runtime.h>
#include <hip/hip_bf16.h>
#include <math.h>
#include <stdint.h>

#define NN 10000
#define EE 100000
#define DD 768
#define HH 4
#define CC 192
#define EDIM 16
#define NREL 10
#define MP 10112           // NN padded to multiple of 128 for GEMM tiles
#define NQKV 3072          // fused output width: [q|k|v|skip]
#define SCALE 0.07216878364870322f   // 1/sqrt(192)

using short8  = __attribute__((ext_vector_type(8))) short;
using floatx4 = __attribute__((ext_vector_type(4))) float;

// ---------------- helpers ----------------

__device__ __forceinline__ float b2f(short u) {
    union { unsigned int i; float f; } t;
    t.i = ((unsigned int)(unsigned short)u) << 16;
    return t.f;
}

__device__ __forceinline__ short f2b(float f) {
    __hip_bfloat16 h = __float2bfloat16(f);
    short r;
    __builtin_memcpy(&r, &h, 2);
    return r;
}

__device__ __forceinline__ __hip_bfloat16 rd_any(const void* p, long long j, int bf) {
    if (bf) return ((const __hip_bfloat16*)p)[j];
    return __float2bfloat16(((const float*)p)[j]);
}

// async global->LDS, 16B per lane; LDS dest must be wave-uniform base + lane*16
__device__ __forceinline__ void gload16(const __hip_bfloat16* g, __hip_bfloat16* l) {
    __builtin_amdgcn_global_load_lds(
        (const __attribute__((address_space(1))) unsigned int*)g,
        (__attribute__((address_space(3))) unsigned int*)l, 16, 0, 0);
}

// ---------------- dtype detection ----------------
__global__ void detect_kernel(const void* edge_attr, int* flag) {
    const unsigned short* p = (const unsigned short*)edge_attr;
    int t = threadIdx.x;
    int nz = (p[4 * t] != 0) ? 1 : 0;
    unsigned long long m = __ballot(nz);
    if (t == 0) *flag = (__popcll(m) > 8) ? 1 : 0;
}

// ---------------- input conversion ----------------

__global__ __launch_bounds__(256) void cvt_big(
    const void* x, const void* We, const int* flag,
    __hip_bfloat16* hb, __hip_bfloat16* Web) {
    long long i = (long long)blockIdx.x * 256 + threadIdx.x;
    int bf = *flag;
    const long long NX = (long long)NN * DD;
    const long long NE2 = 3LL * EDIM * DD;
    if (i < NX) { hb[i] = rd_any(x, i, bf); return; } i -= NX;
    if (i < NE2) { Web[i] = rd_any(We, i, bf); return; } i -= NE2;
    if (i < (long long)(MP - NN) * DD) hb[(long long)NN * DD + i] = __float2bfloat16(0.0f);
}

__global__ __launch_bounds__(256) void cvt_small(
    const void* ea, const void* rel, const void* Wed, const void* bed,
    const void* bk, const void* bq, const void* bv, const void* bs,
    const void* lg, const void* lb, const int* flag,
    __hip_bfloat16* eab, __hip_bfloat16* relb, __hip_bfloat16* Wedb,
    __hip_bfloat16* bedb, __hip_bfloat16* ballb, __hip_bfloat16* lgb,
    __hip_bfloat16* lbb) {
    long long i = (long long)blockIdx.x * 256 + threadIdx.x;
    int bf = *flag;
    if (i < 2LL * EE) { eab[i] = rd_any(ea, i, bf); return; } i -= 2LL * EE;
    if (i < NREL * (EDIM - 1)) { relb[i] = rd_any(rel, i, bf); return; } i -= NREL * (EDIM - 1);
    if (i < EDIM * EDIM) { Wedb[i] = rd_any(Wed, i, bf); return; } i -= EDIM * EDIM;
    if (i < EDIM) { bedb[i] = rd_any(bed, i, bf); return; } i -= EDIM;
    if (i < 3 * NQKV) {
        int l = (int)(i / NQKV), c = (int)(i % NQKV);
        const void* src; long long off;
        if (c < 768)       { src = bq; off = (long long)l * DD + c; }
        else if (c < 1536) { src = bk; off = (long long)l * DD + (c - 768); }
        else if (c < 2304) { src = bv; off = (long long)l * DD + (c - 1536); }
        else               { src = bs; off = (long long)l * DD + (c - 2304); }
        ballb[i] = rd_any(src, off, bf); return;
    } i -= 3 * NQKV;
    if (i < DD) { lgb[i] = rd_any(lg, i, bf); return; } i -= DD;
    if (i < DD) { lbb[i] = rd_any(lb, i, bf); return; }
}

// all-layer fused transposed weights: Wt3[l][n][k], n: [q|k|v|skip]
__global__ __launch_bounds__(256) void wt_all(
    const void* Wq, const void* Wk, const void* Wv, const void* Ws,
    const int* flag, __hip_bfloat16* Wt3) {
    __shared__ __hip_bfloat16 tile[32][33];
    int mm = blockIdx.y;            // l*4 + m
    int l = mm >> 2, m = mm & 3;
    const void* src = (m == 0) ? Wq : (m == 1) ? Wk : (m == 2) ? Wv : Ws;
    int bx = blockIdx.x;            // 24*24 tiles of 32x32
    int tr = bx / 24, tc = bx % 24;
    int k0 = tr * 32, c0 = tc * 32;
    int t = threadIdx.x;
    int rr = t >> 5, cc = t & 31;
    int bf = *flag;
    long long base = (long long)l * DD * DD;
#pragma unroll
    for (int p = 0; p < 4; p++)
        tile[p * 8 + rr][cc] =
            rd_any(src, base + (long long)(k0 + p * 8 + rr) * DD + c0 + cc, bf);
    __syncthreads();
    __hip_bfloat16* dst = Wt3 + (size_t)l * NQKV * DD + (size_t)(m * 768 + c0) * DD + k0;
#pragma unroll
    for (int p = 0; p < 4; p++)
        dst[(size_t)(p * 8 + rr) * DD + cc] = tile[cc][p * 8 + rr];
}

// ---------------- CSR build (incoming edges per dst) ----------------

__global__ __launch_bounds__(256) void zero_counts(int* counts) {
    int i = blockIdx.x * 256 + threadIdx.x;
    if (i < NN) counts[i] = 0;
}

__global__ __launch_bounds__(256) void count_kernel(const int* ei, int* counts) {
    int e = blockIdx.x * 256 + threadIdx.x;
    if (e < EE) atomicAdd(&counts[ei[EE + e]], 1);
}

__global__ __launch_bounds__(256) void scan_kernel(const int* counts, int* rowptr) {
    __shared__ int sdata[256];
    int t = threadIdx.x;
    int base = t * 40;
    int cnt = (base < NN) ? min(40, NN - base) : 0;
    int s = 0;
    for (int i = 0; i < cnt; i++) s += counts[base + i];
    sdata[t] = s;
    __syncthreads();
    for (int off = 1; off < 256; off <<= 1) {
        int add = (t >= off) ? sdata[t - off] : 0;
        __syncthreads();
        sdata[t] += add;
        __syncthreads();
    }
    int run = sdata[t] - s;  // exclusive prefix
    for (int i = 0; i < cnt; i++) {
        run += counts[base + i];
        rowptr[base + i + 1] = run;
    }
    if (t == 0) rowptr[0] = 0;
}

__global__ __launch_bounds__(256) void cursor_kernel(const int* rowptr, int* cursor) {
    int i = blockIdx.x * 256 + threadIdx.x;
    if (i < NN) cursor[i] = rowptr[i];
}

__global__ __launch_bounds__(256) void fill_kernel(const int* ei, int* cursor,
                                                   int* eids, int* esrc) {
    int e = blockIdx.x * 256 + threadIdx.x;
    if (e < EE) {
        int d = ei[EE + e];
        int pos = atomicAdd(&cursor[d], 1);
        eids[pos] = e;
        esrc[pos] = ei[e];
    }
}

// ---------------- edge features (CSR-ordered: ef[p] for CSR slot p) ----------------

__global__ __launch_bounds__(256) void ef_kernel(
    const int* __restrict__ eids,
    const __hip_bfloat16* __restrict__ eab, const __hip_bfloat16* __restrict__ relb,
    const __hip_bfloat16* __restrict__ Wedb, const __hip_bfloat16* __restrict__ bedb,
    float* __restrict__ ef) {
    int idx = blockIdx.x * 256 + threadIdx.x;
    if (idx >= EE * EDIM) return;
    int p = idx >> 4, j = idx & 15;
    int e = eids[p];
    int rid = (int)((float)eab[e * 2 + 0]);
    rid = min(max(rid, 0), NREL - 1);
    float w = (float)eab[e * 2 + 1];
    float s = (float)bedb[j];
#pragma unroll
    for (int i = 0; i < 15; i++)
        s += (float)relb[rid * 15 + i] * (float)Wedb[i * EDIM + j];
    s += w * (float)Wedb[15 * EDIM + j];
    ef[idx] = s;
}

// ---------------- fused GEMM: C[NN,3072] = A[MP,768] @ Wt[3072,768]^T + bias ----
// 128x128 tile, BK=32, async width-16 staging, XOR bank swizzle,
// padded-stride LDS-bounce epilogue (conflict-free staging).

__global__ __launch_bounds__(256) void gemm_fused(
    const __hip_bfloat16* __restrict__ A, const __hip_bfloat16* __restrict__ Bt,
    const __hip_bfloat16* __restrict__ bias, __hip_bfloat16* __restrict__ C) {
    __shared__ __hip_bfloat16 As[128 * 32];   // 8 KB
    __shared__ __hip_bfloat16 Bs[128 * 32];   // 8 KB
    __shared__ __hip_bfloat16 stg[32 * 132];  // 8.25 KB, padded stride 132
    const int tid  = threadIdx.x;
    const int wid  = tid >> 6, lane = tid & 63;
    const int quad = lane >> 4, l15 = lane & 15;
    const int m0 = blockIdx.y * 128, n0 = blockIdx.x * 128;
    const int wm = wid >> 1, wn = wid & 1;
    floatx4 acc[4][4] = {};
    for (int k0 = 0; k0 < DD; k0 += 32) {
#pragma unroll
        for (int j = 0; j < 2; j++) {
            int c = j * 256 + tid;            // chunk index, 16B each
            int r = c >> 2, s = c & 3;
            int ks = s ^ ((r + (r >> 2)) & 3);   // source k-chunk (XOR swizzle)
            gload16(A + (size_t)(m0 + r) * DD + k0 + ks * 8, As + c * 8);
            gload16(Bt + (size_t)(n0 + r) * DD + k0 + ks * 8, Bs + c * 8);
        }
        __syncthreads();
        short8 a[4], b[4];
#pragma unroll
        for (int mt = 0; mt < 4; mt++) {
            int R = wm * 64 + mt * 16 + l15;
            int sw = quad ^ ((R + (R >> 2)) & 3);
            a[mt] = *(const short8*)(As + R * 32 + sw * 8);
        }
#pragma unroll
        for (int nt = 0; nt < 4; nt++) {
            int R = wn * 64 + nt * 16 + l15;
            int sw = quad ^ ((R + (R >> 2)) & 3);
            b[nt] = *(const short8*)(Bs + R * 32 + sw * 8);
        }
#pragma unroll
        for (int mt = 0; mt < 4; mt++)
#pragma unroll
            for (int nt = 0; nt < 4; nt++)
                acc[mt][nt] = __builtin_amdgcn_mfma_f32_16x16x32_bf16(a[mt], b[nt], acc[mt][nt], 0, 0, 0);
        __syncthreads();
    }
    // epilogue: per mt, stage 32 rows (wm*16+quad*4+r) x 128 cols, stride 132
    float bv[4];
#pragma unroll
    for (int nt = 0; nt < 4; nt++) bv[nt] = (float)bias[n0 + wn * 64 + nt * 16 + l15];
    const int rr = tid >> 3, ccs = (tid & 7) * 16;
    const int grow = m0 + (rr >> 4) * 64 + (rr & 15);
    for (int mt = 0; mt < 4; mt++) {
#pragma unroll
        for (int nt = 0; nt < 4; nt++) {
            int col = wn * 64 + nt * 16 + l15;
#pragma unroll
            for (int r = 0; r < 4; r++) {
                int lr = wm * 16 + quad * 4 + r;
                stg[lr * 132 + col] = __float2bfloat16(acc[mt][nt][r] + bv[nt]);
            }
        }
        __syncthreads();
        int row = grow + mt * 16;
        if (row < NN) {
            const short8* sp = (const short8*)(stg + rr * 132 + ccs);
            short8 v0 = sp[0], v1 = sp[1];
            short8* dp = (short8*)(C + (size_t)row * NQKV + n0 + ccs);
            dp[0] = v0; dp[1] = v1;
        }
        __syncthreads();
    }
}

// ---------------- attention ----------------
// qkvs row layout: [q(0) | k(768) | v(1536) | skip(2304)]

// Qe[n,h,j] = dot(q[n, h*C:(h+1)*C], We_l[j, h*C:(h+1)*C]) — short4 vectorized
__global__ __launch_bounds__(256) void qe_kernel(
    const __hip_bfloat16* __restrict__ qkvs, const __hip_bfloat16* __restrict__ Wel,
    float* __restrict__ Qe) {
    int idx = blockIdx.x * 256 + threadIdx.x;
    if (idx >= NN * HH * EDIM) return;
    int n = idx >> 6, hj = idx & 63, hh = hj >> 4, j = hj & 15;
    const short4* qrow = (const short4*)(qkvs + (size_t)n * NQKV + hh * CC);
    const short4* wrow = (const short4*)(Wel + (size_t)j * DD + hh * CC);
    float s = 0.f;
#pragma unroll 8
    for (int c = 0; c < 48; c++) {
        short4 a = qrow[c], b = wrow[c];
        s += b2f(a.x) * b2f(b.x) + b2f(a.y) * b2f(b.y)
           + b2f(a.z) * b2f(b.z) + b2f(a.w) * b2f(b.w);
    }
    Qe[idx] = s;
}

// one wave per node (2500 blocks x 4 waves = 10000 waves): fused alpha +
// online softmax + gather + S@We + skip + gelu. Lane owns channels
// [lane*12, +12). Unroll-by-2 edge pipeline for 2x memory-level parallelism.
__global__ __launch_bounds__(256) void node_attn(
    const int* __restrict__ rowptr, const int* __restrict__ esrc,
    const __hip_bfloat16* __restrict__ qkvs, const float* __restrict__ Qe,
    const float* __restrict__ ef, const __hip_bfloat16* __restrict__ Wel,
    __hip_bfloat16* __restrict__ hb, int do_gelu) {
    const int wid = threadIdx.x >> 6, lane = threadIdx.x & 63;
    const int n = blockIdx.x * 4 + wid;     // grid = 2500 blocks, exact
    const int sj = lane & 15;
    const int hbase = lane & 48;            // head*16
    const int s0 = rowptr[n], s1 = rowptr[n + 1];
    float q[12];
    {
        const short4* qp = (const short4*)(qkvs + (size_t)n * NQKV + lane * 12);
        short4 a = qp[0], b = qp[1], c = qp[2];
        q[0] = b2f(a.x); q[1] = b2f(a.y); q[2]  = b2f(a.z); q[3]  = b2f(a.w);
        q[4] = b2f(b.x); q[5] = b2f(b.y); q[6]  = b2f(b.z); q[7]  = b2f(b.w);
        q[8] = b2f(c.x); q[9] = b2f(c.y); q[10] = b2f(c.z); q[11] = b2f(c.w);
    }
    float qe_l = Qe[n * 64 + lane];
    float m = -INFINITY, lsum = 0.f, sacc = 0.f;
    float acc[12];
#pragma unroll
    for (int i = 0; i < 12; i++) acc[i] = 0.f;
    for (int p = s0; p < s1; p += 2) {
        const int has1 = (p + 1 < s1);
        const int p1 = has1 ? (p + 1) : p;
        const int src0 = esrc[p];
        const int src1 = esrc[p1];
        // issue ALL loads for both edges up front (overlapped latency)
        const short4* kp0 = (const short4*)(qkvs + (size_t)src0 * NQKV + 768 + lane * 12);
        const short4* vp0 = (const short4*)(qkvs + (size_t)src0 * NQKV + 1536 + lane * 12);
        const short4* kp1 = (const short4*)(qkvs + (size_t)src1 * NQKV + 768 + lane * 12);
        const short4* vp1 = (const short4*)(qkvs + (size_t)src1 * NQKV + 1536 + lane * 12);
        short4 k0a = kp0[0], k0b = kp0[1], k0c = kp0[2];
        short4 v0a = vp0[0], v0b = vp0[1], v0c = vp0[2];
        short4 k1a = kp1[0], k1b = kp1[1], k1c = kp1[2];
        short4 v1a = vp1[0], v1b = vp1[1], v1c = vp1[2];
        float ef0 = ef[(size_t)p  * 16 + sj];
        float ef1 = ef[(size_t)p1 * 16 + sj];
        // --- edge 0 ---
        {
            float part = qe_l * ef0;
            part += q[0] * b2f(k0a.x) + q[1] * b2f(k0a.y) + q[2]  * b2f(k0a.z) + q[3]  * b2f(k0a.w);
            part += q[4] * b2f(k0b.x) + q[5] * b2f(k0b.y) + q[6]  * b2f(k0b.z) + q[7]  * b2f(k0b.w);
            part += q[8] * b2f(k0c.x) + q[9] * b2f(k0c.y) + q[10] * b2f(k0c.z) + q[11] * b2f(k0c.w);
            part += __shfl_xor(part, 1); part += __shfl_xor(part, 2);
            part += __shfl_xor(part, 4); part += __shfl_xor(part, 8);
            float a = part * SCALE;
            float nm = fmaxf(m, a);
            float sc = __expf(m - nm);
            float w  = __expf(a - nm);
            lsum = lsum * sc + w;
            m = nm;
            acc[0] = acc[0] * sc + w * b2f(v0a.x); acc[1] = acc[1] * sc + w * b2f(v0a.y);
            acc[2] = acc[2] * sc + w * b2f(v0a.z); acc[3] = acc[3] * sc + w * b2f(v0a.w);
            acc[4] = acc[4] * sc + w * b2f(v0b.x); acc[5] = acc[5] * sc + w * b2f(v0b.y);
            acc[6] = acc[6] * sc + w * b2f(v0b.z); acc[7] = acc[7] * sc + w * b2f(v0b.w);
            acc[8] = acc[8] * sc + w * b2f(v0c.x); acc[9] = acc[9] * sc + w * b2f(v0c.y);
            acc[10] = acc[10] * sc + w * b2f(v0c.z); acc[11] = acc[11] * sc + w * b2f(v0c.w);
            sacc = sacc * sc + w * ef0;
        }
        // --- edge 1 ---
        if (has1) {
            float part = qe_l * ef1;
            part += q[0] * b2f(k1a.x) + q[1] * b2f(k1a.y) + q[2]  * b2f(k1a.z) + q[3]  * b2f(k1a.w);
            part += q[4] * b2f(k1b.x) + q[5] * b2f(k1b.y) + q[6]  * b2f(k1b.z) + q[7]  * b2f(k1b.w);
            part += q[8] * b2f(k1c.x) + q[9] * b2f(k1c.y) + q[10] * b2f(k1c.z) + q[11] * b2f(k1c.w);
            part += __shfl_xor(part, 1); part += __shfl_xor(part, 2);
            part += __shfl_xor(part, 4); part += __shfl_xor(part, 8);
            float a = part * SCALE;
            float nm = fmaxf(m, a);
            float sc = __expf(m - nm);
            float w  = __expf(a - nm);
            lsum = lsum * sc + w;
            m = nm;
            acc[0] = acc[0] * sc + w * b2f(v1a.x); acc[1] = acc[1] * sc + w * b2f(v1a.y);
            acc[2] = acc[2] * sc + w * b2f(v1a.z); acc[3] = acc[3] * sc + w * b2f(v1a.w);
            acc[4] = acc[4] * sc + w * b2f(v1b.x); acc[5] = acc[5] * sc + w * b2f(v1b.y);
            acc[6] = acc[6] * sc + w * b2f(v1b.z); acc[7] = acc[7] * sc + w * b2f(v1b.w);
            acc[8] = acc[8] * sc + w * b2f(v1c.x); acc[9] = acc[9] * sc + w * b2f(v1c.y);
            acc[10] = acc[10] * sc + w * b2f(v1c.z); acc[11] = acc[11] * sc + w * b2f(v1c.w);
            sacc = sacc * sc + w * ef1;
        }
    }
    float inv = 1.0f / (lsum + 1e-16f);
#pragma unroll
    for (int i = 0; i < 12; i++) acc[i] *= inv;
    float sS = sacc * inv;
    // skip connection
    {
        const short4* sp = (const short4*)(qkvs + (size_t)n * NQKV + 2304 + lane * 12);
        short4 a = sp[0], b = sp[1], c = sp[2];
        acc[0] += b2f(a.x); acc[1] += b2f(a.y); acc[2]  += b2f(a.z); acc[3]  += b2f(a.w);
        acc[4] += b2f(b.x); acc[5] += b2f(b.y); acc[6]  += b2f(b.z); acc[7]  += b2f(b.w);
        acc[8] += b2f(c.x); acc[9] += b2f(c.y); acc[10] += b2f(c.z); acc[11] += b2f(c.w);
    }
    // + S @ We (per-head 16-dim): S[h][j] broadcast via shfl
#pragma unroll
    for (int j = 0; j < 16; j++) {
        float sv = __shfl(sS, hbase + j);
        const short4* wp = (const short4*)(Wel + (size_t)j * DD + lane * 12);
        short4 a = wp[0], b = wp[1], c = wp[2];
        acc[0] += sv * b2f(a.x); acc[1] += sv * b2f(a.y);
        acc[2] += sv * b2f(a.z); acc[3] += sv * b2f(a.w);
        acc[4] += sv * b2f(b.x); acc[5] += sv * b2f(b.y);
        acc[6] += sv * b2f(b.z); acc[7] += sv * b2f(b.w);
        acc[8] += sv * b2f(c.x); acc[9] += sv * b2f(c.y);
        acc[10] += sv * b2f(c.z); acc[11] += sv * b2f(c.w);
    }
    if (do_gelu) {
#pragma unroll
        for (int i = 0; i < 12; i++)
            acc[i] = 0.5f * acc[i] * (1.0f + erff(acc[i] * 0.70710678118654752f));
    }
    short4 o0, o1, o2;
    o0.x = f2b(acc[0]); o0.y = f2b(acc[1]); o0.z = f2b(acc[2]); o0.w = f2b(acc[3]);
    o1.x = f2b(acc[4]); o1.y = f2b(acc[5]); o1.z = f2b(acc[6]); o1.w = f2b(acc[7]);
    o2.x = f2b(acc[8]); o2.y = f2b(acc[9]); o2.z = f2b(acc[10]); o2.w = f2b(acc[11]);
    short4* hp = (short4*)(hb + (size_t)n * DD + lane * 12);
    hp[0] = o0; hp[1] = o1; hp[2] = o2;
}

// ---------------- LN + mean pool ----------------

__global__ __launch_bounds__(256) void ln_pool(
    const __hip_bfloat16* __restrict__ hb, const __hip_bfloat16* __restrict__ g,
    const __hip_bfloat16* __restrict__ b, float* __restrict__ partial) {
    __shared__ float sbuf[4][768];
    int grp = blockIdx.x, t = threadIdx.x;
    int wid = t >> 6, lane = t & 63;
    float gv[12], bv[12], acc[12];
#pragma unroll
    for (int i = 0; i < 12; i++) {
        gv[i] = (float)g[lane + i * 64];
        bv[i] = (float)b[lane + i * 64];
        acc[i] = 0.f;
    }
    for (int r = wid; r < 25; r += 4) {
        const __hip_bfloat16* row = hb + (size_t)(grp * 25 + r) * DD;
        float x[12];
        float s = 0.f, q = 0.f;
#pragma unroll
        for (int i = 0; i < 12; i++) {
            x[i] = (float)row[lane + i * 64];
            s += x[i]; q += x[i] * x[i];
        }
#pragma unroll
        for (int m = 32; m > 0; m >>= 1) {
            s += __shfl_xor(s, m); q += __shfl_xor(q, m);
        }
        float mu = s * (1.0f / 768.0f);
        float ms = q * (1.0f / 768.0f);
        float inv = 1.0f / sqrtf(ms - mu * mu + 1e-5f);
#pragma unroll
        for (int i = 0; i < 12; i++)
            acc[i] += (x[i] - mu) * inv * gv[i] + bv[i];
    }
#pragma unroll
    for (int i = 0; i < 12; i++) sbuf[wid][lane + i * 64] = acc[i];
    __syncthreads();
#pragma unroll
    for (int j = 0; j < 3; j++) {
        int col = t + j * 256;
        partial[(size_t)grp * DD + col] =
            sbuf[0][col] + sbuf[1][col] + sbuf[2][col] + sbuf[3][col];
    }
}

__global__ __launch_bounds__(256) void pool1_kernel(
    const float* __restrict__ partial, float* __restrict__ partial2) {
    int idx = blockIdx.x * 256 + threadIdx.x;     // 16*768
    if (idx >= 16 * DD) return;
    int g2 = idx / DD, col = idx % DD;
    float s = 0.f;
    for (int r = 0; r < 25; r++) s += partial[(size_t)(g2 * 25 + r) * DD + col];
    partial2[idx] = s;
}

__global__ __launch_bounds__(256) void pool2_kernel(
    const float* __restrict__ partial2, void* __restrict__ out,
    const int* __restrict__ flag) {
    int dd = blockIdx.x * 256 + threadIdx.x;
    if (dd >= DD) return;
    float s = 0.f;
#pragma unroll
    for (int g2 = 0; g2 < 16; g2++) s += partial2[g2 * DD + dd];
    s *= (1.0f / 10000.0f);
    if (*flag) ((__hip_bfloat16*)out)[dd] = __float2bfloat16(s);
    else ((float*)out)[dd] = s;
}

// ---------------- launch ----------------

extern "C" void kernel_launch(void* const* d_in, const int* in_sizes, int n_in,
                              void* d_out, int out_size, void* d_ws, size_t ws_size,
                              hipStream_t stream) {
    const void* x         = d_in[0];
    const void* edge_attr = d_in[1];
    const int*  ei        = (const int*)d_in[2];
    const void* rel_emb   = d_in[3];
    const void* W_edge    = d_in[4];
    const void* b_edge    = d_in[5];
    const void* Wk        = d_in[6];
    const void* bk        = d_in[7];
    const void* Wq        = d_in[8];
    const void* bq        = d_in[9];
    const void* Wv        = d_in[10];
    const void* bv        = d_in[11];
    const void* We        = d_in[12];
    const void* Wskip     = d_in[13];
    const void* bskip     = d_in[14];
    const void* ln_g      = d_in[15];
    const void* ln_b      = d_in[16];

    char* ws = (char*)d_ws;
    // ---- workspace layout (~102.8 MB total) ----
    int*   flag    = (int*)(ws + 0);
    int*   counts  = (int*)(ws + 256);          // 40,000
    int*   rowptr  = (int*)(ws + 40448);        // 40,004
    int*   cursor  = (int*)(ws + 80640);        // 40,000
    int*   eids    = (int*)(ws + 120832);       // 400,000
    int*   esrc    = (int*)(ws + 520960);       // 400,000
    float* ef      = (float*)(ws + 920960);     // 6,400,000 (CSR-ordered)
    float* Qe      = (float*)(ws + 7320960);    // 2,560,000
    float* partial = (float*)(ws + 9880960);    // 1,228,800
    float* partial2= (float*)(ws + 11109760);   // 49,152
    __hip_bfloat16* eab   = (__hip_bfloat16*)(ws + 11158912);  // 400,000
    __hip_bfloat16* relb  = (__hip_bfloat16*)(ws + 11559296);  // 300
    __hip_bfloat16* Wedb  = (__hip_bfloat16*)(ws + 11559680);  // 512
    __hip_bfloat16* bedb  = (__hip_bfloat16*)(ws + 11560192);  // 32
    __hip_bfloat16* ballb = (__hip_bfloat16*)(ws + 11560320);  // 18,432
    __hip_bfloat16* lngb  = (__hip_bfloat16*)(ws + 11578752);  // 1,536
    __hip_bfloat16* lnbb  = (__hip_bfloat16*)(ws + 11580288);  // 1,536
    __hip_bfloat16* Web   = (__hip_bfloat16*)(ws + 11581824);  // 73,728
    __hip_bfloat16* hb    = (__hip_bfloat16*)(ws + 11655552);  // 15,532,032 (MP*768)
    __hip_bfloat16* Wt3   = (__hip_bfloat16*)(ws + 27187584);  // 14,155,776
    __hip_bfloat16* qkvs  = (__hip_bfloat16*)(ws + 41343360);  // 61,440,000 -> 102,783,360

    dim3 blk(256);

    detect_kernel<<<dim3(1), dim3(64), 0, stream>>>(edge_attr, flag);

    {
        long long tot = (long long)NN * DD + 3LL * EDIM * DD + (long long)(MP - NN) * DD;
        cvt_big<<<dim3((unsigned)((tot + 255) / 256)), blk, 0, stream>>>(x, We, flag, hb, Web);
    }
    {
        long long tot = 2LL * EE + NREL * (EDIM - 1) + EDIM * EDIM + EDIM
                        + 3LL * NQKV + 2LL * DD;
        cvt_small<<<dim3((unsigned)((tot + 255) / 256)), blk, 0, stream>>>(
            edge_attr, rel_emb, W_edge, b_edge, bk, bq, bv, bskip, ln_g, ln_b,
            flag, eab, relb, Wedb, bedb, ballb, lngb, lnbb);
    }
    wt_all<<<dim3(576, 12), blk, 0, stream>>>(Wq, Wk, Wv, Wskip, flag, Wt3);

    // CSR build
    zero_counts<<<dim3(40), blk, 0, stream>>>(counts);
    count_kernel<<<dim3((EE + 255) / 256), blk, 0, stream>>>(ei, counts);
    scan_kernel<<<dim3(1), blk, 0, stream>>>(counts, rowptr);
    cursor_kernel<<<dim3(40), blk, 0, stream>>>(rowptr, cursor);
    fill_kernel<<<dim3((EE + 255) / 256), blk, 0, stream>>>(ei, cursor, eids, esrc);

    ef_kernel<<<dim3((EE * EDIM) / 256), blk, 0, stream>>>(eids, eab, relb, Wedb, bedb, ef);

    for (int l = 0; l < 3; l++) {
        const __hip_bfloat16* We_l = Web + (size_t)l * EDIM * DD;
        gemm_fused<<<dim3(NQKV / 128, MP / 128), blk, 0, stream>>>(
            hb, Wt3 + (size_t)l * NQKV * DD, ballb + (size_t)l * NQKV, qkvs);
        qe_kernel<<<dim3((NN * 64) / 256), blk, 0, stream>>>(qkvs, We_l, Qe);
        node_attn<<<dim3(NN / 4), blk, 0, stream>>>(rowptr, esrc, qkvs, Qe, ef,
                                                    We_l, hb, (l < 2) ? 1 : 0);
    }

    ln_pool<<<dim3(400), blk, 0, stream>>>(hb, lngb, lnbb, partial);
    pool1_kernel<<<dim3(48), blk, 0, stream>>>(partial, partial2);
    pool2_kernel<<<dim3(3), blk, 0, stream>>>(partial2, d_out, flag);
}

// Round 7
// 749.080 us; speedup vs baseline: 1.2649x; 1.0139x over previous
//
#include <hip/hip_runtime.h>
#include <hip/hip_bf16.h>
#include <math.h>
#include <stdint.h>

#define NN 10000
#define EE 100000
#define DD 768
#define HH 4
#define CC 192
#define EDIM 16
#define NREL 10
#define MP 10112           // NN padded to multiple of 128 for GEMM tiles
#define NQ2 3200           // fused output width: [q|k|v|skip|Qe(64)|pad(64)]
#define SCALE 0.07216878364870322f   // 1/sqrt(192)

using short8  = __attribute__((ext_vector_type(8))) short;
using floatx4 = __attribute__((ext_vector_type(4))) float;

// ---------------- helpers ----------------

__device__ __forceinline__ float b2f(short u) {
    union { unsigned int i; float f; } t;
    t.i = ((unsigned int)(unsigned short)u) << 16;
    return t.f;
}

__device__ __forceinline__ short f2b(float f) {
    __hip_bfloat16 h = __float2bfloat16(f);
    short r;
    __builtin_memcpy(&r, &h, 2);
    return r;
}

__device__ __forceinline__ __hip_bfloat16 rd_any(const void* p, long long j, int bf) {
    if (bf) return ((const __hip_bfloat16*)p)[j];
    return __float2bfloat16(((const float*)p)[j]);
}

// async global->LDS, 16B per lane; LDS dest must be wave-uniform base + lane*16
__device__ __forceinline__ void gload16(const __hip_bfloat16* g, __hip_bfloat16* l) {
    __builtin_amdgcn_global_load_lds(
        (const __attribute__((address_space(1))) unsigned int*)g,
        (__attribute__((address_space(3))) unsigned int*)l, 16, 0, 0);
}

// ---------------- dtype detection ----------------
__global__ void detect_kernel(const void* edge_attr, int* flag) {
    const unsigned short* p = (const unsigned short*)edge_attr;
    int t = threadIdx.x;
    int nz = (p[4 * t] != 0) ? 1 : 0;
    unsigned long long m = __ballot(nz);
    if (t == 0) *flag = (__popcll(m) > 8) ? 1 : 0;
}

// ---------------- input conversion ----------------

__global__ __launch_bounds__(256) void cvt_big(
    const void* x, const void* We, const int* flag,
    __hip_bfloat16* hb, __hip_bfloat16* Web) {
    long long i = (long long)blockIdx.x * 256 + threadIdx.x;
    int bf = *flag;
    const long long NX = (long long)NN * DD;
    const long long NE2 = 3LL * EDIM * DD;
    if (i < NX) { hb[i] = rd_any(x, i, bf); return; } i -= NX;
    if (i < NE2) { Web[i] = rd_any(We, i, bf); return; } i -= NE2;
    if (i < (long long)(MP - NN) * DD) hb[(long long)NN * DD + i] = __float2bfloat16(0.0f);
}

__global__ __launch_bounds__(256) void cvt_small(
    const void* ea, const void* rel, const void* Wed, const void* bed,
    const void* bk, const void* bq, const void* bv, const void* bs,
    const void* lg, const void* lb, const int* flag,
    __hip_bfloat16* eab, __hip_bfloat16* relb, __hip_bfloat16* Wedb,
    __hip_bfloat16* bedb, __hip_bfloat16* ballb, __hip_bfloat16* lgb,
    __hip_bfloat16* lbb) {
    long long i = (long long)blockIdx.x * 256 + threadIdx.x;
    int bf = *flag;
    if (i < 2LL * EE) { eab[i] = rd_any(ea, i, bf); return; } i -= 2LL * EE;
    if (i < NREL * (EDIM - 1)) { relb[i] = rd_any(rel, i, bf); return; } i -= NREL * (EDIM - 1);
    if (i < EDIM * EDIM) { Wedb[i] = rd_any(Wed, i, bf); return; } i -= EDIM * EDIM;
    if (i < EDIM) { bedb[i] = rd_any(bed, i, bf); return; } i -= EDIM;
    if (i < 3 * NQ2) {
        int l = (int)(i / NQ2), c = (int)(i % NQ2);
        const void* src; long long off;
        if (c < 768)       { src = bq; off = (long long)l * DD + c; }
        else if (c < 1536) { src = bk; off = (long long)l * DD + (c - 768); }
        else if (c < 2304) { src = bv; off = (long long)l * DD + (c - 1536); }
        else if (c < 3072) { src = bs; off = (long long)l * DD + (c - 2304); }
        else { ballb[i] = __float2bfloat16(0.0f); return; }  // Qe bias filled by mq_kernel
        ballb[i] = rd_any(src, off, bf); return;
    } i -= 3 * NQ2;
    if (i < DD) { lgb[i] = rd_any(lg, i, bf); return; } i -= DD;
    if (i < DD) { lbb[i] = rd_any(lb, i, bf); return; }
}

// all-layer fused transposed weights: Wt3[l][n][k], n: [q|k|v|skip|...]
__global__ __launch_bounds__(256) void wt_all(
    const void* Wq, const void* Wk, const void* Wv, const void* Ws,
    const int* flag, __hip_bfloat16* Wt3) {
    __shared__ __hip_bfloat16 tile[32][33];
    int mm = blockIdx.y;            // l*4 + m
    int l = mm >> 2, m = mm & 3;
    const void* src = (m == 0) ? Wq : (m == 1) ? Wk : (m == 2) ? Wv : Ws;
    int bx = blockIdx.x;            // 24*24 tiles of 32x32
    int tr = bx / 24, tc = bx % 24;
    int k0 = tr * 32, c0 = tc * 32;
    int t = threadIdx.x;
    int rr = t >> 5, cc = t & 31;
    int bf = *flag;
    long long base = (long long)l * DD * DD;
#pragma unroll
    for (int p = 0; p < 4; p++)
        tile[p * 8 + rr][cc] =
            rd_any(src, base + (long long)(k0 + p * 8 + rr) * DD + c0 + cc, bf);
    __syncthreads();
    __hip_bfloat16* dst = Wt3 + (size_t)l * NQ2 * DD + (size_t)(m * 768 + c0) * DD + k0;
#pragma unroll
    for (int p = 0; p < 4; p++)
        dst[(size_t)(p * 8 + rr) * DD + cc] = tile[cc][p * 8 + rr];
}

// Qe-columns of Wt3: Wt3[l][3072+hj][k] = sum_c Wq[l][k][h*CC+c]*We[l][j][h*CC+c]
// plus Qe bias into ballb[l][3072+hj]; cols 3136..3199 zeroed.
__global__ __launch_bounds__(256) void mq_kernel(
    const void* Wq, const void* bq, const int* flag,
    const __hip_bfloat16* __restrict__ Web, __hip_bfloat16* Wt3,
    __hip_bfloat16* ballb) {
    int idx = blockIdx.x * 256 + threadIdx.x;   // 3 * 128 * 768
    if (idx >= 3 * 128 * DD) return;
    int l = idx / (128 * DD);
    int rem = idx % (128 * DD);
    int hj = rem / DD, k = rem % DD;
    if (hj >= 64) {   // pad columns -> zero
        Wt3[(size_t)l * NQ2 * DD + (size_t)(3072 + hj) * DD + k] = __float2bfloat16(0.0f);
        return;
    }
    int hh = hj >> 4, j = hj & 15;
    int bf = *flag;
    const __hip_bfloat16* wrow = Web + (size_t)l * EDIM * DD + (size_t)j * DD + hh * CC;
    long long qbase = ((long long)l * DD + k) * DD + hh * CC;
    float s = 0.f;
    for (int c = 0; c < CC; c++)
        s += (float)rd_any(Wq, qbase + c, bf) * (float)wrow[c];
    Wt3[(size_t)l * NQ2 * DD + (size_t)(3072 + hj) * DD + k] = __float2bfloat16(s);
    if (k == 0) {
        float b = 0.f;
        for (int c = 0; c < CC; c++)
            b += (float)rd_any(bq, (long long)l * DD + hh * CC + c, bf) * (float)wrow[c];
        ballb[l * NQ2 + 3072 + hj] = __float2bfloat16(b);
    }
}

// ---------------- CSR build (incoming edges per dst) ----------------

__global__ __launch_bounds__(256) void zero_counts(int* counts) {
    int i = blockIdx.x * 256 + threadIdx.x;
    if (i < NN) counts[i] = 0;
}

__global__ __launch_bounds__(256) void count_kernel(const int* ei, int* counts) {
    int e = blockIdx.x * 256 + threadIdx.x;
    if (e < EE) atomicAdd(&counts[ei[EE + e]], 1);
}

__global__ __launch_bounds__(256) void scan_kernel(const int* counts, int* rowptr) {
    __shared__ int sdata[256];
    int t = threadIdx.x;
    int base = t * 40;
    int cnt = (base < NN) ? min(40, NN - base) : 0;
    int s = 0;
    for (int i = 0; i < cnt; i++) s += counts[base + i];
    sdata[t] = s;
    __syncthreads();
    for (int off = 1; off < 256; off <<= 1) {
        int add = (t >= off) ? sdata[t - off] : 0;
        __syncthreads();
        sdata[t] += add;
        __syncthreads();
    }
    int run = sdata[t] - s;  // exclusive prefix
    for (int i = 0; i < cnt; i++) {
        run += counts[base + i];
        rowptr[base + i + 1] = run;
    }
    if (t == 0) rowptr[0] = 0;
}

__global__ __launch_bounds__(256) void cursor_kernel(const int* rowptr, int* cursor) {
    int i = blockIdx.x * 256 + threadIdx.x;
    if (i < NN) cursor[i] = rowptr[i];
}

__global__ __launch_bounds__(256) void fill_kernel(const int* ei, int* cursor,
                                                   int* eids, int* esrc) {
    int e = blockIdx.x * 256 + threadIdx.x;
    if (e < EE) {
        int d = ei[EE + e];
        int pos = atomicAdd(&cursor[d], 1);
        eids[pos] = e;
        esrc[pos] = ei[e];
    }
}

// ---------------- edge features (CSR-ordered, bf16) ----------------

__global__ __launch_bounds__(256) void ef_kernel(
    const int* __restrict__ eids,
    const __hip_bfloat16* __restrict__ eab, const __hip_bfloat16* __restrict__ relb,
    const __hip_bfloat16* __restrict__ Wedb, const __hip_bfloat16* __restrict__ bedb,
    __hip_bfloat16* __restrict__ efb) {
    int idx = blockIdx.x * 256 + threadIdx.x;
    if (idx >= EE * EDIM) return;
    int p = idx >> 4, j = idx & 15;
    int e = eids[p];
    int rid = (int)((float)eab[e * 2 + 0]);
    rid = min(max(rid, 0), NREL - 1);
    float w = (float)eab[e * 2 + 1];
    float s = (float)bedb[j];
#pragma unroll
    for (int i = 0; i < 15; i++)
        s += (float)relb[rid * 15 + i] * (float)Wedb[i * EDIM + j];
    s += w * (float)Wedb[15 * EDIM + j];
    efb[idx] = __float2bfloat16(s);
}

// ---------------- fused GEMM: C[NN,3200] = A[MP,768] @ Wt[3200,768]^T + bias ----
// 128x128 tile, BK=32, async width-16 staging, padded LDS-bounce epilogue.

__global__ __launch_bounds__(256) void gemm_fused(
    const __hip_bfloat16* __restrict__ A, const __hip_bfloat16* __restrict__ Bt,
    const __hip_bfloat16* __restrict__ bias, __hip_bfloat16* __restrict__ C) {
    __shared__ __hip_bfloat16 As[128 * 32];   // 8 KB
    __shared__ __hip_bfloat16 Bs[128 * 32];   // 8 KB
    __shared__ __hip_bfloat16 stg[32 * 132];  // 8.25 KB, padded stride 132
    const int tid  = threadIdx.x;
    const int wid  = tid >> 6, lane = tid & 63;
    const int quad = lane >> 4, l15 = lane & 15;
    const int m0 = blockIdx.y * 128, n0 = blockIdx.x * 128;
    const int wm = wid >> 1, wn = wid & 1;
    floatx4 acc[4][4] = {};
    for (int k0 = 0; k0 < DD; k0 += 32) {
#pragma unroll
        for (int j = 0; j < 2; j++) {
            int c = j * 256 + tid;            // chunk index, 16B each
            int r = c >> 2, s = c & 3;
            int ks = s ^ ((r + (r >> 2)) & 3);   // XOR swizzle (harmless; kept)
            gload16(A + (size_t)(m0 + r) * DD + k0 + ks * 8, As + c * 8);
            gload16(Bt + (size_t)(n0 + r) * DD + k0 + ks * 8, Bs + c * 8);
        }
        __syncthreads();
        short8 a[4], b[4];
#pragma unroll
        for (int mt = 0; mt < 4; mt++) {
            int R = wm * 64 + mt * 16 + l15;
            int sw = quad ^ ((R + (R >> 2)) & 3);
            a[mt] = *(const short8*)(As + R * 32 + sw * 8);
        }
#pragma unroll
        for (int nt = 0; nt < 4; nt++) {
            int R = wn * 64 + nt * 16 + l15;
            int sw = quad ^ ((R + (R >> 2)) & 3);
            b[nt] = *(const short8*)(Bs + R * 32 + sw * 8);
        }
#pragma unroll
        for (int mt = 0; mt < 4; mt++)
#pragma unroll
            for (int nt = 0; nt < 4; nt++)
                acc[mt][nt] = __builtin_amdgcn_mfma_f32_16x16x32_bf16(a[mt], b[nt], acc[mt][nt], 0, 0, 0);
        __syncthreads();
    }
    float bv[4];
#pragma unroll
    for (int nt = 0; nt < 4; nt++) bv[nt] = (float)bias[n0 + wn * 64 + nt * 16 + l15];
    const int rr = tid >> 3, ccs = (tid & 7) * 16;
    const int grow = m0 + (rr >> 4) * 64 + (rr & 15);
    for (int mt = 0; mt < 4; mt++) {
#pragma unroll
        for (int nt = 0; nt < 4; nt++) {
            int col = wn * 64 + nt * 16 + l15;
#pragma unroll
            for (int r = 0; r < 4; r++) {
                int lr = wm * 16 + quad * 4 + r;
                stg[lr * 132 + col] = __float2bfloat16(acc[mt][nt][r] + bv[nt]);
            }
        }
        __syncthreads();
        int row = grow + mt * 16;
        if (row < NN) {
            const short8* sp = (const short8*)(stg + rr * 132 + ccs);
            short8 v0 = sp[0], v1 = sp[1];
            short8* dp = (short8*)(C + (size_t)row * NQ2 + n0 + ccs);
            dp[0] = v0; dp[1] = v1;
        }
        __syncthreads();
    }
}

// ---------------- attention ----------------
// qkvs row layout (stride 3200): [q(0) | k(768) | v(1536) | skip(2304) | Qe(3072)]

// one wave per node (2500 blocks x 4 waves): fused alpha + online softmax +
// gather + S@We + skip + gelu. Lane owns channels [lane*12, +12).
__global__ __launch_bounds__(256) void node_attn(
    const int* __restrict__ rowptr, const int* __restrict__ esrc,
    const __hip_bfloat16* __restrict__ qkvs, const __hip_bfloat16* __restrict__ efb,
    const __hip_bfloat16* __restrict__ Wel, __hip_bfloat16* __restrict__ hb,
    int do_gelu) {
    const int wid = threadIdx.x >> 6, lane = threadIdx.x & 63;
    const int n = blockIdx.x * 4 + wid;     // grid = 2500 blocks, exact
    const int sj = lane & 15;
    const int hbase = lane & 48;            // head*16
    const int s0 = rowptr[n], s1 = rowptr[n + 1];
    float q[12];
    {
        const short4* qp = (const short4*)(qkvs + (size_t)n * NQ2 + lane * 12);
        short4 a = qp[0], b = qp[1], c = qp[2];
        q[0] = b2f(a.x); q[1] = b2f(a.y); q[2]  = b2f(a.z); q[3]  = b2f(a.w);
        q[4] = b2f(b.x); q[5] = b2f(b.y); q[6]  = b2f(b.z); q[7]  = b2f(b.w);
        q[8] = b2f(c.x); q[9] = b2f(c.y); q[10] = b2f(c.z); q[11] = b2f(c.w);
    }
    float qe_l = b2f(((const short*)qkvs)[(size_t)n * NQ2 + 3072 + lane]);
    float m = -INFINITY, lsum = 0.f, sacc = 0.f;
    float acc[12];
#pragma unroll
    for (int i = 0; i < 12; i++) acc[i] = 0.f;
    for (int p = s0; p < s1; p++) {
        int src = esrc[p];
        const short4* kp = (const short4*)(qkvs + (size_t)src * NQ2 + 768 + lane * 12);
        const short4* vp = (const short4*)(qkvs + (size_t)src * NQ2 + 1536 + lane * 12);
        short4 ka = kp[0], kb = kp[1], kc = kp[2];
        short4 va = vp[0], vb = vp[1], vc = vp[2];
        float efv = b2f(((const short*)efb)[(size_t)p * 16 + sj]);
        float part = qe_l * efv;
        part += q[0] * b2f(ka.x) + q[1] * b2f(ka.y) + q[2]  * b2f(ka.z) + q[3]  * b2f(ka.w);
        part += q[4] * b2f(kb.x) + q[5] * b2f(kb.y) + q[6]  * b2f(kb.z) + q[7]  * b2f(kb.w);
        part += q[8] * b2f(kc.x) + q[9] * b2f(kc.y) + q[10] * b2f(kc.z) + q[11] * b2f(kc.w);
        part += __shfl_xor(part, 1); part += __shfl_xor(part, 2);
        part += __shfl_xor(part, 4); part += __shfl_xor(part, 8);
        float a = part * SCALE;
        float nm = fmaxf(m, a);
        float sc = __expf(m - nm);
        float w  = __expf(a - nm);
        lsum = lsum * sc + w;
        m = nm;
        acc[0] = acc[0] * sc + w * b2f(va.x); acc[1] = acc[1] * sc + w * b2f(va.y);
        acc[2] = acc[2] * sc + w * b2f(va.z); acc[3] = acc[3] * sc + w * b2f(va.w);
        acc[4] = acc[4] * sc + w * b2f(vb.x); acc[5] = acc[5] * sc + w * b2f(vb.y);
        acc[6] = acc[6] * sc + w * b2f(vb.z); acc[7] = acc[7] * sc + w * b2f(vb.w);
        acc[8] = acc[8] * sc + w * b2f(vc.x); acc[9] = acc[9] * sc + w * b2f(vc.y);
        acc[10] = acc[10] * sc + w * b2f(vc.z); acc[11] = acc[11] * sc + w * b2f(vc.w);
        sacc = sacc * sc + w * efv;
    }
    float inv = 1.0f / (lsum + 1e-16f);
#pragma unroll
    for (int i = 0; i < 12; i++) acc[i] *= inv;
    float sS = sacc * inv;
    // skip connection
    {
        const short4* sp = (const short4*)(qkvs + (size_t)n * NQ2 + 2304 + lane * 12);
        short4 a = sp[0], b = sp[1], c = sp[2];
        acc[0] += b2f(a.x); acc[1] += b2f(a.y); acc[2]  += b2f(a.z); acc[3]  += b2f(a.w);
        acc[4] += b2f(b.x); acc[5] += b2f(b.y); acc[6]  += b2f(b.z); acc[7]  += b2f(b.w);
        acc[8] += b2f(c.x); acc[9] += b2f(c.y); acc[10] += b2f(c.z); acc[11] += b2f(c.w);
    }
    // + S @ We (per-head 16-dim): S[h][j] broadcast via shfl
#pragma unroll
    for (int j = 0; j < 16; j++) {
        float sv = __shfl(sS, hbase + j);
        const short4* wp = (const short4*)(Wel + (size_t)j * DD + lane * 12);
        short4 a = wp[0], b = wp[1], c = wp[2];
        acc[0] += sv * b2f(a.x); acc[1] += sv * b2f(a.y);
        acc[2] += sv * b2f(a.z); acc[3] += sv * b2f(a.w);
        acc[4] += sv * b2f(b.x); acc[5] += sv * b2f(b.y);
        acc[6] += sv * b2f(b.z); acc[7] += sv * b2f(b.w);
        acc[8] += sv * b2f(c.x); acc[9] += sv * b2f(c.y);
        acc[10] += sv * b2f(c.z); acc[11] += sv * b2f(c.w);
    }
    if (do_gelu) {
#pragma unroll
        for (int i = 0; i < 12; i++)
            acc[i] = 0.5f * acc[i] * (1.0f + erff(acc[i] * 0.70710678118654752f));
    }
    short4 o0, o1, o2;
    o0.x = f2b(acc[0]); o0.y = f2b(acc[1]); o0.z = f2b(acc[2]); o0.w = f2b(acc[3]);
    o1.x = f2b(acc[4]); o1.y = f2b(acc[5]); o1.z = f2b(acc[6]); o1.w = f2b(acc[7]);
    o2.x = f2b(acc[8]); o2.y = f2b(acc[9]); o2.z = f2b(acc[10]); o2.w = f2b(acc[11]);
    short4* hp = (short4*)(hb + (size_t)n * DD + lane * 12);
    hp[0] = o0; hp[1] = o1; hp[2] = o2;
}

// ---------------- LN + mean pool ----------------

__global__ __launch_bounds__(256) void ln_pool(
    const __hip_bfloat16* __restrict__ hb, const __hip_bfloat16* __restrict__ g,
    const __hip_bfloat16* __restrict__ b, float* __restrict__ partial) {
    __shared__ float sbuf[4][768];
    int grp = blockIdx.x, t = threadIdx.x;
    int wid = t >> 6, lane = t & 63;
    float gv[12], bv[12], acc[12];
#pragma unroll
    for (int i = 0; i < 12; i++) {
        gv[i] = (float)g[lane + i * 64];
        bv[i] = (float)b[lane + i * 64];
        acc[i] = 0.f;
    }
    for (int r = wid; r < 25; r += 4) {
        const __hip_bfloat16* row = hb + (size_t)(grp * 25 + r) * DD;
        float x[12];
        float s = 0.f, q = 0.f;
#pragma unroll
        for (int i = 0; i < 12; i++) {
            x[i] = (float)row[lane + i * 64];
            s += x[i]; q += x[i] * x[i];
        }
#pragma unroll
        for (int m = 32; m > 0; m >>= 1) {
            s += __shfl_xor(s, m); q += __shfl_xor(q, m);
        }
        float mu = s * (1.0f / 768.0f);
        float ms = q * (1.0f / 768.0f);
        float inv = 1.0f / sqrtf(ms - mu * mu + 1e-5f);
#pragma unroll
        for (int i = 0; i < 12; i++)
            acc[i] += (x[i] - mu) * inv * gv[i] + bv[i];
    }
#pragma unroll
    for (int i = 0; i < 12; i++) sbuf[wid][lane + i * 64] = acc[i];
    __syncthreads();
#pragma unroll
    for (int j = 0; j < 3; j++) {
        int col = t + j * 256;
        partial[(size_t)grp * DD + col] =
            sbuf[0][col] + sbuf[1][col] + sbuf[2][col] + sbuf[3][col];
    }
}

__global__ __launch_bounds__(256) void pool1_kernel(
    const float* __restrict__ partial, float* __restrict__ partial2) {
    int idx = blockIdx.x * 256 + threadIdx.x;     // 16*768
    if (idx >= 16 * DD) return;
    int g2 = idx / DD, col = idx % DD;
    float s = 0.f;
    for (int r = 0; r < 25; r++) s += partial[(size_t)(g2 * 25 + r) * DD + col];
    partial2[idx] = s;
}

__global__ __launch_bounds__(256) void pool2_kernel(
    const float* __restrict__ partial2, void* __restrict__ out,
    const int* __restrict__ flag) {
    int dd = blockIdx.x * 256 + threadIdx.x;
    if (dd >= DD) return;
    float s = 0.f;
#pragma unroll
    for (int g2 = 0; g2 < 16; g2++) s += partial2[g2 * DD + dd];
    s *= (1.0f / 10000.0f);
    if (*flag) ((__hip_bfloat16*)out)[dd] = __float2bfloat16(s);
    else ((float*)out)[dd] = s;
}

// ---------------- launch ----------------

extern "C" void kernel_launch(void* const* d_in, const int* in_sizes, int n_in,
                              void* d_out, int out_size, void* d_ws, size_t ws_size,
                              hipStream_t stream) {
    const void* x         = d_in[0];
    const void* edge_attr = d_in[1];
    const int*  ei        = (const int*)d_in[2];
    const void* rel_emb   = d_in[3];
    const void* W_edge    = d_in[4];
    const void* b_edge    = d_in[5];
    const void* Wk        = d_in[6];
    const void* bk        = d_in[7];
    const void* Wq        = d_in[8];
    const void* bq        = d_in[9];
    const void* Wv        = d_in[10];
    const void* bv        = d_in[11];
    const void* We        = d_in[12];
    const void* Wskip     = d_in[13];
    const void* bskip     = d_in[14];
    const void* ln_g      = d_in[15];
    const void* ln_b      = d_in[16];

    char* ws = (char*)d_ws;
    // ---- workspace layout (~100.2 MB total) ----
    int*   flag    = (int*)(ws + 0);
    int*   counts  = (int*)(ws + 256);          // 40,000
    int*   rowptr  = (int*)(ws + 40448);        // 40,004
    int*   cursor  = (int*)(ws + 80640);        // 40,000
    int*   eids    = (int*)(ws + 120832);       // 400,000
    int*   esrc    = (int*)(ws + 520960);       // 400,000
    __hip_bfloat16* efb = (__hip_bfloat16*)(ws + 920960);   // 3,200,000 (CSR-ordered)
    float* partial = (float*)(ws + 4120960);    // 1,228,800
    float* partial2= (float*)(ws + 5349760);    // 49,152
    __hip_bfloat16* eab   = (__hip_bfloat16*)(ws + 5398912);  // 400,000
    __hip_bfloat16* relb  = (__hip_bfloat16*)(ws + 5799296);  // 300
    __hip_bfloat16* Wedb  = (__hip_bfloat16*)(ws + 5799680);  // 512
    __hip_bfloat16* bedb  = (__hip_bfloat16*)(ws + 5800192);  // 32
    __hip_bfloat16* ballb = (__hip_bfloat16*)(ws + 5800320);  // 19,200 (3*3200)
    __hip_bfloat16* lngb  = (__hip_bfloat16*)(ws + 5819520);  // 1,536
    __hip_bfloat16* lnbb  = (__hip_bfloat16*)(ws + 5821056);  // 1,536
    __hip_bfloat16* Web   = (__hip_bfloat16*)(ws + 5822592);  // 73,728
    __hip_bfloat16* hb    = (__hip_bfloat16*)(ws + 5896320);  // 15,532,032 (MP*768)
    __hip_bfloat16* Wt3   = (__hip_bfloat16*)(ws + 21428352); // 14,745,600 (3*3200*768)
    __hip_bfloat16* qkvs  = (__hip_bfloat16*)(ws + 36173952); // 64,000,000 -> 100,173,952

    dim3 blk(256);

    detect_kernel<<<dim3(1), dim3(64), 0, stream>>>(edge_attr, flag);

    {
        long long tot = (long long)NN * DD + 3LL * EDIM * DD + (long long)(MP - NN) * DD;
        cvt_big<<<dim3((unsigned)((tot + 255) / 256)), blk, 0, stream>>>(x, We, flag, hb, Web);
    }
    {
        long long tot = 2LL * EE + NREL * (EDIM - 1) + EDIM * EDIM + EDIM
                        + 3LL * NQ2 + 2LL * DD;
        cvt_small<<<dim3((unsigned)((tot + 255) / 256)), blk, 0, stream>>>(
            edge_attr, rel_emb, W_edge, b_edge, bk, bq, bv, bskip, ln_g, ln_b,
            flag, eab, relb, Wedb, bedb, ballb, lngb, lnbb);
    }
    wt_all<<<dim3(576, 12), blk, 0, stream>>>(Wq, Wk, Wv, Wskip, flag, Wt3);
    mq_kernel<<<dim3((3 * 128 * DD) / 256), blk, 0, stream>>>(Wq, bq, flag, Web, Wt3, ballb);

    // CSR build
    zero_counts<<<dim3(40), blk, 0, stream>>>(counts);
    count_kernel<<<dim3((EE + 255) / 256), blk, 0, stream>>>(ei, counts);
    scan_kernel<<<dim3(1), blk, 0, stream>>>(counts, rowptr);
    cursor_kernel<<<dim3(40), blk, 0, stream>>>(rowptr, cursor);
    fill_kernel<<<dim3((EE + 255) / 256), blk, 0, stream>>>(ei, cursor, eids, esrc);

    ef_kernel<<<dim3((EE * EDIM) / 256), blk, 0, stream>>>(eids, eab, relb, Wedb, bedb, efb);

    for (int l = 0; l < 3; l++) {
        const __hip_bfloat16* We_l = Web + (size_t)l * EDIM * DD;
        gemm_fused<<<dim3(NQ2 / 128, MP / 128), blk, 0, stream>>>(
            hb, Wt3 + (size_t)l * NQ2 * DD, ballb + (size_t)l * NQ2, qkvs);
        node_attn<<<dim3(NN / 4), blk, 0, stream>>>(rowptr, esrc, qkvs, efb,
                                                    We_l, hb, (l < 2) ? 1 : 0);
    }

    ln_pool<<<dim3(400), blk, 0, stream>>>(hb, lngb, lnbb, partial);
    pool1_kernel<<<dim3(48), blk, 0, stream>>>(partial, partial2);
    pool2_kernel<<<dim3(3), blk, 0, stream>>>(partial2, d_out, flag);
}

// Round 8
// 644.999 us; speedup vs baseline: 1.4690x; 1.1614x over previous
//
#include <hip/hip_runtime.h>
#include <hip/hip_bf16.h>
#include <math.h>
#include <stdint.h>

#define NN 10000
#define EE 100000
#define DD 768
#define HH 4
#define CC 192
#define EDIM 16
#define NREL 10
#define MP 10112           // NN padded to multiple of 128 for GEMM tiles
#define NQ2 3200           // fused output width: [q|k|v|skip|Qe(64)|pad(64)]
#define SCALE 0.07216878364870322f   // 1/sqrt(192)

using short8  = __attribute__((ext_vector_type(8))) short;
using floatx4 = __attribute__((ext_vector_type(4))) float;

// ---------------- helpers ----------------

__device__ __forceinline__ float b2f(short u) {
    union { unsigned int i; float f; } t;
    t.i = ((unsigned int)(unsigned short)u) << 16;
    return t.f;
}

__device__ __forceinline__ short f2b(float f) {
    __hip_bfloat16 h = __float2bfloat16(f);
    short r;
    __builtin_memcpy(&r, &h, 2);
    return r;
}

__device__ __forceinline__ __hip_bfloat16 rd_any(const void* p, long long j, int bf) {
    if (bf) return ((const __hip_bfloat16*)p)[j];
    return __float2bfloat16(((const float*)p)[j]);
}

// async global->LDS, 16B per lane; LDS dest must be wave-uniform base + lane*16
__device__ __forceinline__ void gload16(const __hip_bfloat16* g, __hip_bfloat16* l) {
    __builtin_amdgcn_global_load_lds(
        (const __attribute__((address_space(1))) unsigned int*)g,
        (__attribute__((address_space(3))) unsigned int*)l, 16, 0, 0);
}

// ---------------- dtype detection ----------------
__global__ void detect_kernel(const void* edge_attr, int* flag) {
    const unsigned short* p = (const unsigned short*)edge_attr;
    int t = threadIdx.x;
    int nz = (p[4 * t] != 0) ? 1 : 0;
    unsigned long long m = __ballot(nz);
    if (t == 0) *flag = (__popcll(m) > 8) ? 1 : 0;
}

// ---------------- input conversion ----------------

__global__ __launch_bounds__(256) void cvt_big(
    const void* x, const void* We, const int* flag,
    __hip_bfloat16* hb, __hip_bfloat16* Web) {
    long long i = (long long)blockIdx.x * 256 + threadIdx.x;
    int bf = *flag;
    const long long NX = (long long)NN * DD;
    const long long NE2 = 3LL * EDIM * DD;
    if (i < NX) { hb[i] = rd_any(x, i, bf); return; } i -= NX;
    if (i < NE2) { Web[i] = rd_any(We, i, bf); return; } i -= NE2;
    if (i < (long long)(MP - NN) * DD) hb[(long long)NN * DD + i] = __float2bfloat16(0.0f);
}

__global__ __launch_bounds__(256) void cvt_small(
    const void* ea, const void* rel, const void* Wed, const void* bed,
    const void* bk, const void* bq, const void* bv, const void* bs,
    const void* lg, const void* lb, const int* flag,
    __hip_bfloat16* eab, __hip_bfloat16* relb, __hip_bfloat16* Wedb,
    __hip_bfloat16* bedb, __hip_bfloat16* ballb, __hip_bfloat16* lgb,
    __hip_bfloat16* lbb) {
    long long i = (long long)blockIdx.x * 256 + threadIdx.x;
    int bf = *flag;
    if (i < 2LL * EE) { eab[i] = rd_any(ea, i, bf); return; } i -= 2LL * EE;
    if (i < NREL * (EDIM - 1)) { relb[i] = rd_any(rel, i, bf); return; } i -= NREL * (EDIM - 1);
    if (i < EDIM * EDIM) { Wedb[i] = rd_any(Wed, i, bf); return; } i -= EDIM * EDIM;
    if (i < EDIM) { bedb[i] = rd_any(bed, i, bf); return; } i -= EDIM;
    if (i < 3 * NQ2) {
        int l = (int)(i / NQ2), c = (int)(i % NQ2);
        const void* src; long long off;
        if (c < 768)       { src = bq; off = (long long)l * DD + c; }
        else if (c < 1536) { src = bk; off = (long long)l * DD + (c - 768); }
        else if (c < 2304) { src = bv; off = (long long)l * DD + (c - 1536); }
        else if (c < 3072) { src = bs; off = (long long)l * DD + (c - 2304); }
        else { ballb[i] = __float2bfloat16(0.0f); return; }  // Qe bias filled by mq_kernel
        ballb[i] = rd_any(src, off, bf); return;
    } i -= 3 * NQ2;
    if (i < DD) { lgb[i] = rd_any(lg, i, bf); return; } i -= DD;
    if (i < DD) { lbb[i] = rd_any(lb, i, bf); return; }
}

// all-layer fused transposed weights: Wt3[l][n][k], n: [q|k|v|skip|...]
__global__ __launch_bounds__(256) void wt_all(
    const void* Wq, const void* Wk, const void* Wv, const void* Ws,
    const int* flag, __hip_bfloat16* Wt3) {
    __shared__ __hip_bfloat16 tile[32][33];
    int mm = blockIdx.y;            // l*4 + m
    int l = mm >> 2, m = mm & 3;
    const void* src = (m == 0) ? Wq : (m == 1) ? Wk : (m == 2) ? Wv : Ws;
    int bx = blockIdx.x;            // 24*24 tiles of 32x32
    int tr = bx / 24, tc = bx % 24;
    int k0 = tr * 32, c0 = tc * 32;
    int t = threadIdx.x;
    int rr = t >> 5, cc = t & 31;
    int bf = *flag;
    long long base = (long long)l * DD * DD;
#pragma unroll
    for (int p = 0; p < 4; p++)
        tile[p * 8 + rr][cc] =
            rd_any(src, base + (long long)(k0 + p * 8 + rr) * DD + c0 + cc, bf);
    __syncthreads();
    __hip_bfloat16* dst = Wt3 + (size_t)l * NQ2 * DD + (size_t)(m * 768 + c0) * DD + k0;
#pragma unroll
    for (int p = 0; p < 4; p++)
        dst[(size_t)(p * 8 + rr) * DD + cc] = tile[cc][p * 8 + rr];
}

// Qe-columns of Wt3: Wt3[l][3072+hj][k] = sum_c Wq[l][k][h*CC+c]*We[l][j][h*CC+c]
// Blocked: grid (12 kchunks x 12 lh); We head-slice staged in LDS; Wq rows read
// with contiguous vector loads. Also zeroes pad rows 3136..3199 and fills the
// Qe bias (bq . We-slice) into ballb.
__global__ __launch_bounds__(256) void mq_kernel(
    const void* Wq, const void* bq, const int* flag,
    const __hip_bfloat16* __restrict__ Web, __hip_bfloat16* __restrict__ Wt3,
    __hip_bfloat16* __restrict__ ballb) {
    __shared__ float WeS[16][193];
    const int lh = blockIdx.y, l = lh >> 2, hh = lh & 3;
    const int t = threadIdx.x;
    const int bf = *flag;
    for (int i = t; i < 16 * 192; i += 256) {
        int j = i / 192, c = i % 192;
        WeS[j][c] = (float)Web[(size_t)l * EDIM * DD + (size_t)j * DD + hh * CC + c];
    }
    __syncthreads();
    const int k = blockIdx.x * 64 + (t >> 2);
    const int j0 = (t & 3) * 4;
    float s0 = 0.f, s1 = 0.f, s2 = 0.f, s3 = 0.f;
    if (bf) {
        const short8* qp = (const short8*)((const __hip_bfloat16*)Wq +
            ((size_t)l * DD + k) * DD + hh * CC);
#pragma unroll 4
        for (int ch = 0; ch < 24; ch++) {
            short8 v = qp[ch];
#pragma unroll
            for (int u = 0; u < 8; u++) {
                float w = b2f(v[u]);
                int c = ch * 8 + u;
                s0 += w * WeS[j0 + 0][c]; s1 += w * WeS[j0 + 1][c];
                s2 += w * WeS[j0 + 2][c]; s3 += w * WeS[j0 + 3][c];
            }
        }
    } else {
        const float4* qp = (const float4*)((const float*)Wq +
            ((size_t)l * DD + k) * DD + hh * CC);
#pragma unroll 4
        for (int ch = 0; ch < 48; ch++) {
            float4 v = qp[ch];
            float wv[4] = {v.x, v.y, v.z, v.w};
#pragma unroll
            for (int u = 0; u < 4; u++) {
                float w = wv[u];
                int c = ch * 4 + u;
                s0 += w * WeS[j0 + 0][c]; s1 += w * WeS[j0 + 1][c];
                s2 += w * WeS[j0 + 2][c]; s3 += w * WeS[j0 + 3][c];
            }
        }
    }
    const size_t base = (size_t)l * NQ2 * DD;
    const int row = 3072 + hh * 16 + j0;
    Wt3[base + (size_t)(row + 0) * DD + k] = __float2bfloat16(s0);
    Wt3[base + (size_t)(row + 1) * DD + k] = __float2bfloat16(s1);
    Wt3[base + (size_t)(row + 2) * DD + k] = __float2bfloat16(s2);
    Wt3[base + (size_t)(row + 3) * DD + k] = __float2bfloat16(s3);
    const int prow = 3136 + hh * 16 + j0;
#pragma unroll
    for (int i = 0; i < 4; i++)
        Wt3[base + (size_t)(prow + i) * DD + k] = __float2bfloat16(0.0f);
    if (blockIdx.x == 0 && t < 4) {       // k==0 lane group: j0 = t*4
        float b0 = 0.f, b1 = 0.f, b2 = 0.f, b3 = 0.f;
        for (int c = 0; c < CC; c++) {
            float w = (float)rd_any(bq, (long long)l * DD + hh * CC + c, bf);
            b0 += w * WeS[j0 + 0][c]; b1 += w * WeS[j0 + 1][c];
            b2 += w * WeS[j0 + 2][c]; b3 += w * WeS[j0 + 3][c];
        }
        ballb[l * NQ2 + 3072 + hh * 16 + j0 + 0] = __float2bfloat16(b0);
        ballb[l * NQ2 + 3072 + hh * 16 + j0 + 1] = __float2bfloat16(b1);
        ballb[l * NQ2 + 3072 + hh * 16 + j0 + 2] = __float2bfloat16(b2);
        ballb[l * NQ2 + 3072 + hh * 16 + j0 + 3] = __float2bfloat16(b3);
    }
}

// ---------------- CSR build (incoming edges per dst) ----------------

__global__ __launch_bounds__(256) void zero_counts(int* counts) {
    int i = blockIdx.x * 256 + threadIdx.x;
    if (i < NN) counts[i] = 0;
}

__global__ __launch_bounds__(256) void count_kernel(const int* ei, int* counts) {
    int e = blockIdx.x * 256 + threadIdx.x;
    if (e < EE) atomicAdd(&counts[ei[EE + e]], 1);
}

__global__ __launch_bounds__(256) void scan_kernel(const int* counts, int* rowptr) {
    __shared__ int sdata[256];
    int t = threadIdx.x;
    int base = t * 40;
    int cnt = (base < NN) ? min(40, NN - base) : 0;
    int s = 0;
    for (int i = 0; i < cnt; i++) s += counts[base + i];
    sdata[t] = s;
    __syncthreads();
    for (int off = 1; off < 256; off <<= 1) {
        int add = (t >= off) ? sdata[t - off] : 0;
        __syncthreads();
        sdata[t] += add;
        __syncthreads();
    }
    int run = sdata[t] - s;  // exclusive prefix
    for (int i = 0; i < cnt; i++) {
        run += counts[base + i];
        rowptr[base + i + 1] = run;
    }
    if (t == 0) rowptr[0] = 0;
}

__global__ __launch_bounds__(256) void cursor_kernel(const int* rowptr, int* cursor) {
    int i = blockIdx.x * 256 + threadIdx.x;
    if (i < NN) cursor[i] = rowptr[i];
}

__global__ __launch_bounds__(256) void fill_kernel(const int* ei, int* cursor,
                                                   int* eids, int* esrc) {
    int e = blockIdx.x * 256 + threadIdx.x;
    if (e < EE) {
        int d = ei[EE + e];
        int pos = atomicAdd(&cursor[d], 1);
        eids[pos] = e;
        esrc[pos] = ei[e];
    }
}

// ---------------- edge features (CSR-ordered, bf16) ----------------

__global__ __launch_bounds__(256) void ef_kernel(
    const int* __restrict__ eids,
    const __hip_bfloat16* __restrict__ eab, const __hip_bfloat16* __restrict__ relb,
    const __hip_bfloat16* __restrict__ Wedb, const __hip_bfloat16* __restrict__ bedb,
    __hip_bfloat16* __restrict__ efb) {
    int idx = blockIdx.x * 256 + threadIdx.x;
    if (idx >= EE * EDIM) return;
    int p = idx >> 4, j = idx & 15;
    int e = eids[p];
    int rid = (int)((float)eab[e * 2 + 0]);
    rid = min(max(rid, 0), NREL - 1);
    float w = (float)eab[e * 2 + 1];
    float s = (float)bedb[j];
#pragma unroll
    for (int i = 0; i < 15; i++)
        s += (float)relb[rid * 15 + i] * (float)Wedb[i * EDIM + j];
    s += w * (float)Wedb[15 * EDIM + j];
    efb[idx] = __float2bfloat16(s);
}

// ---------------- fused GEMM: C[NN,3200] = A[MP,768] @ Wt[3200,768]^T + bias ----
// 128x128 tile, BK=32, async width-16 staging, padded LDS-bounce epilogue.

__global__ __launch_bounds__(256) void gemm_fused(
    const __hip_bfloat16* __restrict__ A, const __hip_bfloat16* __restrict__ Bt,
    const __hip_bfloat16* __restrict__ bias, __hip_bfloat16* __restrict__ C) {
    __shared__ __hip_bfloat16 As[128 * 32];   // 8 KB
    __shared__ __hip_bfloat16 Bs[128 * 32];   // 8 KB
    __shared__ __hip_bfloat16 stg[32 * 132];  // 8.25 KB, padded stride 132
    const int tid  = threadIdx.x;
    const int wid  = tid >> 6, lane = tid & 63;
    const int quad = lane >> 4, l15 = lane & 15;
    const int m0 = blockIdx.y * 128, n0 = blockIdx.x * 128;
    const int wm = wid >> 1, wn = wid & 1;
    floatx4 acc[4][4] = {};
    for (int k0 = 0; k0 < DD; k0 += 32) {
#pragma unroll
        for (int j = 0; j < 2; j++) {
            int c = j * 256 + tid;            // chunk index, 16B each
            int r = c >> 2, s = c & 3;
            int ks = s ^ ((r + (r >> 2)) & 3);   // XOR swizzle
            gload16(A + (size_t)(m0 + r) * DD + k0 + ks * 8, As + c * 8);
            gload16(Bt + (size_t)(n0 + r) * DD + k0 + ks * 8, Bs + c * 8);
        }
        __syncthreads();
        short8 a[4], b[4];
#pragma unroll
        for (int mt = 0; mt < 4; mt++) {
            int R = wm * 64 + mt * 16 + l15;
            int sw = quad ^ ((R + (R >> 2)) & 3);
            a[mt] = *(const short8*)(As + R * 32 + sw * 8);
        }
#pragma unroll
        for (int nt = 0; nt < 4; nt++) {
            int R = wn * 64 + nt * 16 + l15;
            int sw = quad ^ ((R + (R >> 2)) & 3);
            b[nt] = *(const short8*)(Bs + R * 32 + sw * 8);
        }
#pragma unroll
        for (int mt = 0; mt < 4; mt++)
#pragma unroll
            for (int nt = 0; nt < 4; nt++)
                acc[mt][nt] = __builtin_amdgcn_mfma_f32_16x16x32_bf16(a[mt], b[nt], acc[mt][nt], 0, 0, 0);
        __syncthreads();
    }
    float bv[4];
#pragma unroll
    for (int nt = 0; nt < 4; nt++) bv[nt] = (float)bias[n0 + wn * 64 + nt * 16 + l15];
    const int rr = tid >> 3, ccs = (tid & 7) * 16;
    const int grow = m0 + (rr >> 4) * 64 + (rr & 15);
    for (int mt = 0; mt < 4; mt++) {
#pragma unroll
        for (int nt = 0; nt < 4; nt++) {
            int col = wn * 64 + nt * 16 + l15;
#pragma unroll
            for (int r = 0; r < 4; r++) {
                int lr = wm * 16 + quad * 4 + r;
                stg[lr * 132 + col] = __float2bfloat16(acc[mt][nt][r] + bv[nt]);
            }
        }
        __syncthreads();
        int row = grow + mt * 16;
        if (row < NN) {
            const short8* sp = (const short8*)(stg + rr * 132 + ccs);
            short8 v0 = sp[0], v1 = sp[1];
            short8* dp = (short8*)(C + (size_t)row * NQ2 + n0 + ccs);
            dp[0] = v0; dp[1] = v1;
        }
        __syncthreads();
    }
}

// ---------------- attention ----------------
// qkvs row layout (stride 3200): [q(0) | k(768) | v(1536) | skip(2304) | Qe(3072)]

// one wave per node (2500 blocks x 4 waves): fused alpha + online softmax +
// gather + S@We + skip + gelu. Lane owns channels [lane*12, +12).
__global__ __launch_bounds__(256) void node_attn(
    const int* __restrict__ rowptr, const int* __restrict__ esrc,
    const __hip_bfloat16* __restrict__ qkvs, const __hip_bfloat16* __restrict__ efb,
    const __hip_bfloat16* __restrict__ Wel, __hip_bfloat16* __restrict__ hb,
    int do_gelu) {
    const int wid = threadIdx.x >> 6, lane = threadIdx.x & 63;
    const int n = blockIdx.x * 4 + wid;     // grid = 2500 blocks, exact
    const int sj = lane & 15;
    const int hbase = lane & 48;            // head*16
    const int s0 = rowptr[n], s1 = rowptr[n + 1];
    float q[12];
    {
        const short4* qp = (const short4*)(qkvs + (size_t)n * NQ2 + lane * 12);
        short4 a = qp[0], b = qp[1], c = qp[2];
        q[0] = b2f(a.x); q[1] = b2f(a.y); q[2]  = b2f(a.z); q[3]  = b2f(a.w);
        q[4] = b2f(b.x); q[5] = b2f(b.y); q[6]  = b2f(b.z); q[7]  = b2f(b.w);
        q[8] = b2f(c.x); q[9] = b2f(c.y); q[10] = b2f(c.z); q[11] = b2f(c.w);
    }
    float qe_l = b2f(((const short*)qkvs)[(size_t)n * NQ2 + 3072 + lane]);
    float m = -INFINITY, lsum = 0.f, sacc = 0.f;
    float acc[12];
#pragma unroll
    for (int i = 0; i < 12; i++) acc[i] = 0.f;
    for (int p = s0; p < s1; p++) {
        int src = esrc[p];
        const short4* kp = (const short4*)(qkvs + (size_t)src * NQ2 + 768 + lane * 12);
        const short4* vp = (const short4*)(qkvs + (size_t)src * NQ2 + 1536 + lane * 12);
        short4 ka = kp[0], kb = kp[1], kc = kp[2];
        short4 va = vp[0], vb = vp[1], vc = vp[2];
        float efv = b2f(((const short*)efb)[(size_t)p * 16 + sj]);
        float part = qe_l * efv;
        part += q[0] * b2f(ka.x) + q[1] * b2f(ka.y) + q[2]  * b2f(ka.z) + q[3]  * b2f(ka.w);
        part += q[4] * b2f(kb.x) + q[5] * b2f(kb.y) + q[6]  * b2f(kb.z) + q[7]  * b2f(kb.w);
        part += q[8] * b2f(kc.x) + q[9] * b2f(kc.y) + q[10] * b2f(kc.z) + q[11] * b2f(kc.w);
        part += __shfl_xor(part, 1); part += __shfl_xor(part, 2);
        part += __shfl_xor(part, 4); part += __shfl_xor(part, 8);
        float a = part * SCALE;
        float nm = fmaxf(m, a);
        float sc = __expf(m - nm);
        float w  = __expf(a - nm);
        lsum = lsum * sc + w;
        m = nm;
        acc[0] = acc[0] * sc + w * b2f(va.x); acc[1] = acc[1] * sc + w * b2f(va.y);
        acc[2] = acc[2] * sc + w * b2f(va.z); acc[3] = acc[3] * sc + w * b2f(va.w);
        acc[4] = acc[4] * sc + w * b2f(vb.x); acc[5] = acc[5] * sc + w * b2f(vb.y);
        acc[6] = acc[6] * sc + w * b2f(vb.z); acc[7] = acc[7] * sc + w * b2f(vb.w);
        acc[8] = acc[8] * sc + w * b2f(vc.x); acc[9] = acc[9] * sc + w * b2f(vc.y);
        acc[10] = acc[10] * sc + w * b2f(vc.z); acc[11] = acc[11] * sc + w * b2f(vc.w);
        sacc = sacc * sc + w * efv;
    }
    float inv = 1.0f / (lsum + 1e-16f);
#pragma unroll
    for (int i = 0; i < 12; i++) acc[i] *= inv;
    float sS = sacc * inv;
    // skip connection
    {
        const short4* sp = (const short4*)(qkvs + (size_t)n * NQ2 + 2304 + lane * 12);
        short4 a = sp[0], b = sp[1], c = sp[2];
        acc[0] += b2f(a.x); acc[1] += b2f(a.y); acc[2]  += b2f(a.z); acc[3]  += b2f(a.w);
        acc[4] += b2f(b.x); acc[5] += b2f(b.y); acc[6]  += b2f(b.z); acc[7]  += b2f(b.w);
        acc[8] += b2f(c.x); acc[9] += b2f(c.y); acc[10] += b2f(c.z); acc[11] += b2f(c.w);
    }
    // + S @ We (per-head 16-dim): S[h][j] broadcast via shfl
#pragma unroll
    for (int j = 0; j < 16; j++) {
        float sv = __shfl(sS, hbase + j);
        const short4* wp = (const short4*)(Wel + (size_t)j * DD + lane * 12);
        short4 a = wp[0], b = wp[1], c = wp[2];
        acc[0] += sv * b2f(a.x); acc[1] += sv * b2f(a.y);
        acc[2] += sv * b2f(a.z); acc[3] += sv * b2f(a.w);
        acc[4] += sv * b2f(b.x); acc[5] += sv * b2f(b.y);
        acc[6] += sv * b2f(b.z); acc[7] += sv * b2f(b.w);
        acc[8] += sv * b2f(c.x); acc[9] += sv * b2f(c.y);
        acc[10] += sv * b2f(c.z); acc[11] += sv * b2f(c.w);
    }
    if (do_gelu) {
#pragma unroll
        for (int i = 0; i < 12; i++)
            acc[i] = 0.5f * acc[i] * (1.0f + erff(acc[i] * 0.70710678118654752f));
    }
    short4 o0, o1, o2;
    o0.x = f2b(acc[0]); o0.y = f2b(acc[1]); o0.z = f2b(acc[2]); o0.w = f2b(acc[3]);
    o1.x = f2b(acc[4]); o1.y = f2b(acc[5]); o1.z = f2b(acc[6]); o1.w = f2b(acc[7]);
    o2.x = f2b(acc[8]); o2.y = f2b(acc[9]); o2.z = f2b(acc[10]); o2.w = f2b(acc[11]);
    short4* hp = (short4*)(hb + (size_t)n * DD + lane * 12);
    hp[0] = o0; hp[1] = o1; hp[2] = o2;
}

// ---------------- LN + mean pool ----------------

__global__ __launch_bounds__(256) void ln_pool(
    const __hip_bfloat16* __restrict__ hb, const __hip_bfloat16* __restrict__ g,
    const __hip_bfloat16* __restrict__ b, float* __restrict__ partial) {
    __shared__ float sbuf[4][768];
    int grp = blockIdx.x, t = threadIdx.x;
    int wid = t >> 6, lane = t & 63;
    float gv[12], bv[12], acc[12];
#pragma unroll
    for (int i = 0; i < 12; i++) {
        gv[i] = (float)g[lane + i * 64];
        bv[i] = (float)b[lane + i * 64];
        acc[i] = 0.f;
    }
    for (int r = wid; r < 25; r += 4) {
        const __hip_bfloat16* row = hb + (size_t)(grp * 25 + r) * DD;
        float x[12];
        float s = 0.f, q = 0.f;
#pragma unroll
        for (int i = 0; i < 12; i++) {
            x[i] = (float)row[lane + i * 64];
            s += x[i]; q += x[i] * x[i];
        }
#pragma unroll
        for (int m = 32; m > 0; m >>= 1) {
            s += __shfl_xor(s, m); q += __shfl_xor(q, m);
        }
        float mu = s * (1.0f / 768.0f);
        float ms = q * (1.0f / 768.0f);
        float inv = 1.0f / sqrtf(ms - mu * mu + 1e-5f);
#pragma unroll
        for (int i = 0; i < 12; i++)
            acc[i] += (x[i] - mu) * inv * gv[i] + bv[i];
    }
#pragma unroll
    for (int i = 0; i < 12; i++) sbuf[wid][lane + i * 64] = acc[i];
    __syncthreads();
#pragma unroll
    for (int j = 0; j < 3; j++) {
        int col = t + j * 256;
        partial[(size_t)grp * DD + col] =
            sbuf[0][col] + sbuf[1][col] + sbuf[2][col] + sbuf[3][col];
    }
}

__global__ __launch_bounds__(256) void pool1_kernel(
    const float* __restrict__ partial, float* __restrict__ partial2) {
    int idx = blockIdx.x * 256 + threadIdx.x;     // 16*768
    if (idx >= 16 * DD) return;
    int g2 = idx / DD, col = idx % DD;
    float s = 0.f;
    for (int r = 0; r < 25; r++) s += partial[(size_t)(g2 * 25 + r) * DD + col];
    partial2[idx] = s;
}

__global__ __launch_bounds__(256) void pool2_kernel(
    const float* __restrict__ partial2, void* __restrict__ out,
    const int* __restrict__ flag) {
    int dd = blockIdx.x * 256 + threadIdx.x;
    if (dd >= DD) return;
    float s = 0.f;
#pragma unroll
    for (int g2 = 0; g2 < 16; g2++) s += partial2[g2 * DD + dd];
    s *= (1.0f / 10000.0f);
    if (*flag) ((__hip_bfloat16*)out)[dd] = __float2bfloat16(s);
    else ((float*)out)[dd] = s;
}

// ---------------- launch ----------------

extern "C" void kernel_launch(void* const* d_in, const int* in_sizes, int n_in,
                              void* d_out, int out_size, void* d_ws, size_t ws_size,
                              hipStream_t stream) {
    const void* x         = d_in[0];
    const void* edge_attr = d_in[1];
    const int*  ei        = (const int*)d_in[2];
    const void* rel_emb   = d_in[3];
    const void* W_edge    = d_in[4];
    const void* b_edge    = d_in[5];
    const void* Wk        = d_in[6];
    const void* bk        = d_in[7];
    const void* Wq        = d_in[8];
    const void* bq        = d_in[9];
    const void* Wv        = d_in[10];
    const void* bv        = d_in[11];
    const void* We        = d_in[12];
    const void* Wskip     = d_in[13];
    const void* bskip     = d_in[14];
    const void* ln_g      = d_in[15];
    const void* ln_b      = d_in[16];

    char* ws = (char*)d_ws;
    // ---- workspace layout (~100.2 MB total) ----
    int*   flag    = (int*)(ws + 0);
    int*   counts  = (int*)(ws + 256);          // 40,000
    int*   rowptr  = (int*)(ws + 40448);        // 40,004
    int*   cursor  = (int*)(ws + 80640);        // 40,000
    int*   eids    = (int*)(ws + 120832);       // 400,000
    int*   esrc    = (int*)(ws + 520960);       // 400,000
    __hip_bfloat16* efb = (__hip_bfloat16*)(ws + 920960);   // 3,200,000 (CSR-ordered)
    float* partial = (float*)(ws + 4120960);    // 1,228,800
    float* partial2= (float*)(ws + 5349760);    // 49,152
    __hip_bfloat16* eab   = (__hip_bfloat16*)(ws + 5398912);  // 400,000
    __hip_bfloat16* relb  = (__hip_bfloat16*)(ws + 5799296);  // 300
    __hip_bfloat16* Wedb  = (__hip_bfloat16*)(ws + 5799680);  // 512
    __hip_bfloat16* bedb  = (__hip_bfloat16*)(ws + 5800192);  // 32
    __hip_bfloat16* ballb = (__hip_bfloat16*)(ws + 5800320);  // 19,200 (3*3200)
    __hip_bfloat16* lngb  = (__hip_bfloat16*)(ws + 5819520);  // 1,536
    __hip_bfloat16* lnbb  = (__hip_bfloat16*)(ws + 5821056);  // 1,536
    __hip_bfloat16* Web   = (__hip_bfloat16*)(ws + 5822592);  // 73,728
    __hip_bfloat16* hb    = (__hip_bfloat16*)(ws + 5896320);  // 15,532,032 (MP*768)
    __hip_bfloat16* Wt3   = (__hip_bfloat16*)(ws + 21428352); // 14,745,600 (3*3200*768)
    __hip_bfloat16* qkvs  = (__hip_bfloat16*)(ws + 36173952); // 64,000,000 -> 100,173,952

    dim3 blk(256);

    detect_kernel<<<dim3(1), dim3(64), 0, stream>>>(edge_attr, flag);

    {
        long long tot = (long long)NN * DD + 3LL * EDIM * DD + (long long)(MP - NN) * DD;
        cvt_big<<<dim3((unsigned)((tot + 255) / 256)), blk, 0, stream>>>(x, We, flag, hb, Web);
    }
    {
        long long tot = 2LL * EE + NREL * (EDIM - 1) + EDIM * EDIM + EDIM
                        + 3LL * NQ2 + 2LL * DD;
        cvt_small<<<dim3((unsigned)((tot + 255) / 256)), blk, 0, stream>>>(
            edge_attr, rel_emb, W_edge, b_edge, bk, bq, bv, bskip, ln_g, ln_b,
            flag, eab, relb, Wedb, bedb, ballb, lngb, lnbb);
    }
    wt_all<<<dim3(576, 12), blk, 0, stream>>>(Wq, Wk, Wv, Wskip, flag, Wt3);
    mq_kernel<<<dim3(12, 12), blk, 0, stream>>>(Wq, bq, flag, Web, Wt3, ballb);

    // CSR build
    zero_counts<<<dim3(40), blk, 0, stream>>>(counts);
    count_kernel<<<dim3((EE + 255) / 256), blk, 0, stream>>>(ei, counts);
    scan_kernel<<<dim3(1), blk, 0, stream>>>(counts, rowptr);
    cursor_kernel<<<dim3(40), blk, 0, stream>>>(rowptr, cursor);
    fill_kernel<<<dim3((EE + 255) / 256), blk, 0, stream>>>(ei, cursor, eids, esrc);

    ef_kernel<<<dim3((EE * EDIM) / 256), blk, 0, stream>>>(eids, eab, relb, Wedb, bedb, efb);

    for (int l = 0; l < 3; l++) {
        const __hip_bfloat16* We_l = Web + (size_t)l * EDIM * DD;
        gemm_fused<<<dim3(NQ2 / 128, MP / 128), blk, 0, stream>>>(
            hb, Wt3 + (size_t)l * NQ2 * DD, ballb + (size_t)l * NQ2, qkvs);
        node_attn<<<dim3(NN / 4), blk, 0, stream>>>(rowptr, esrc, qkvs, efb,
                                                    We_l, hb, (l < 2) ? 1 : 0);
    }

    ln_pool<<<dim3(400), blk, 0, stream>>>(hb, lngb, lnbb, partial);
    pool1_kernel<<<dim3(48), blk, 0, stream>>>(partial, partial2);
    pool2_kernel<<<dim3(3), blk, 0, stream>>>(partial2, d_out, flag);
}

// Round 9
// 633.067 us; speedup vs baseline: 1.4967x; 1.0188x over previous
//
#include <hip/hip_runtime.h>
#include <hip/hip_bf16.h>
#include <math.h>
#include <stdint.h>

#define NN 10000
#define EE 100000
#define DD 768
#define HH 4
#define CC 192
#define EDIM 16
#define NREL 10
#define MP 10112           // NN padded to multiple of 128 for GEMM tiles
#define NQ2 3200           // fused output width: [q|k|v|skip|Qe(64)|pad(64)]
#define SCALE 0.07216878364870322f   // 1/sqrt(192)

using short8  = __attribute__((ext_vector_type(8))) short;
using floatx4 = __attribute__((ext_vector_type(4))) float;

// ---------------- helpers ----------------

__device__ __forceinline__ float b2f(short u) {
    union { unsigned int i; float f; } t;
    t.i = ((unsigned int)(unsigned short)u) << 16;
    return t.f;
}

__device__ __forceinline__ short f2b(float f) {
    __hip_bfloat16 h = __float2bfloat16(f);
    short r;
    __builtin_memcpy(&r, &h, 2);
    return r;
}

__device__ __forceinline__ __hip_bfloat16 rd_any(const void* p, long long j, int bf) {
    if (bf) return ((const __hip_bfloat16*)p)[j];
    return __float2bfloat16(((const float*)p)[j]);
}

// async global->LDS, 16B per lane; LDS dest must be wave-uniform base + lane*16
__device__ __forceinline__ void gload16(const __hip_bfloat16* g, __hip_bfloat16* l) {
    __builtin_amdgcn_global_load_lds(
        (const __attribute__((address_space(1))) unsigned int*)g,
        (__attribute__((address_space(3))) unsigned int*)l, 16, 0, 0);
}

// ---------------- dtype detect + zero counts (fused) ----------------
__global__ __launch_bounds__(256) void detect_zero(const void* edge_attr,
                                                   int* flag, int* counts) {
    int i = blockIdx.x * 256 + threadIdx.x;
    if (i < NN) counts[i] = 0;
    if (blockIdx.x == 0 && threadIdx.x < 64) {
        const unsigned short* p = (const unsigned short*)edge_attr;
        int nz = (p[4 * threadIdx.x] != 0) ? 1 : 0;
        unsigned long long m = __ballot(nz);
        if (threadIdx.x == 0) *flag = (__popcll(m) > 8) ? 1 : 0;
    }
}

// ---------------- input conversion ----------------

__global__ __launch_bounds__(256) void cvt_big(
    const void* x, const void* We, const int* flag,
    __hip_bfloat16* hb, __hip_bfloat16* Web) {
    long long i = (long long)blockIdx.x * 256 + threadIdx.x;
    int bf = *flag;
    const long long NX = (long long)NN * DD;
    const long long NE2 = 3LL * EDIM * DD;
    if (i < NX) { hb[i] = rd_any(x, i, bf); return; } i -= NX;
    if (i < NE2) { Web[i] = rd_any(We, i, bf); return; } i -= NE2;
    if (i < (long long)(MP - NN) * DD) hb[(long long)NN * DD + i] = __float2bfloat16(0.0f);
}

__global__ __launch_bounds__(256) void cvt_small(
    const void* ea, const void* rel, const void* Wed, const void* bed,
    const void* bk, const void* bq, const void* bv, const void* bs,
    const void* lg, const void* lb, const int* flag,
    __hip_bfloat16* eab, __hip_bfloat16* relb, __hip_bfloat16* Wedb,
    __hip_bfloat16* bedb, __hip_bfloat16* ballb, __hip_bfloat16* lgb,
    __hip_bfloat16* lbb) {
    long long i = (long long)blockIdx.x * 256 + threadIdx.x;
    int bf = *flag;
    if (i < 2LL * EE) { eab[i] = rd_any(ea, i, bf); return; } i -= 2LL * EE;
    if (i < NREL * (EDIM - 1)) { relb[i] = rd_any(rel, i, bf); return; } i -= NREL * (EDIM - 1);
    if (i < EDIM * EDIM) { Wedb[i] = rd_any(Wed, i, bf); return; } i -= EDIM * EDIM;
    if (i < EDIM) { bedb[i] = rd_any(bed, i, bf); return; } i -= EDIM;
    if (i < 3 * NQ2) {
        int l = (int)(i / NQ2), c = (int)(i % NQ2);
        const void* src; long long off;
        if (c < 768)       { src = bq; off = (long long)l * DD + c; }
        else if (c < 1536) { src = bk; off = (long long)l * DD + (c - 768); }
        else if (c < 2304) { src = bv; off = (long long)l * DD + (c - 1536); }
        else if (c < 3072) { src = bs; off = (long long)l * DD + (c - 2304); }
        else { ballb[i] = __float2bfloat16(0.0f); return; }  // Qe bias filled by mq_kernel
        ballb[i] = rd_any(src, off, bf); return;
    } i -= 3 * NQ2;
    if (i < DD) { lgb[i] = rd_any(lg, i, bf); return; } i -= DD;
    if (i < DD) { lbb[i] = rd_any(lb, i, bf); return; }
}

// all-layer fused transposed weights: Wt3[l][n][k], n: [q|k|v|skip|...]
__global__ __launch_bounds__(256) void wt_all(
    const void* Wq, const void* Wk, const void* Wv, const void* Ws,
    const int* flag, __hip_bfloat16* Wt3) {
    __shared__ __hip_bfloat16 tile[32][33];
    int mm = blockIdx.y;            // l*4 + m
    int l = mm >> 2, m = mm & 3;
    const void* src = (m == 0) ? Wq : (m == 1) ? Wk : (m == 2) ? Wv : Ws;
    int bx = blockIdx.x;            // 24*24 tiles of 32x32
    int tr = bx / 24, tc = bx % 24;
    int k0 = tr * 32, c0 = tc * 32;
    int t = threadIdx.x;
    int rr = t >> 5, cc = t & 31;
    int bf = *flag;
    long long base = (long long)l * DD * DD;
#pragma unroll
    for (int p = 0; p < 4; p++)
        tile[p * 8 + rr][cc] =
            rd_any(src, base + (long long)(k0 + p * 8 + rr) * DD + c0 + cc, bf);
    __syncthreads();
    __hip_bfloat16* dst = Wt3 + (size_t)l * NQ2 * DD + (size_t)(m * 768 + c0) * DD + k0;
#pragma unroll
    for (int p = 0; p < 4; p++)
        dst[(size_t)(p * 8 + rr) * DD + cc] = tile[cc][p * 8 + rr];
}

// Qe-columns of Wt3: Wt3[l][3072+hj][k] = sum_c Wq[l][k][h*CC+c]*We[l][j][h*CC+c]
__global__ __launch_bounds__(256) void mq_kernel(
    const void* Wq, const void* bq, const int* flag,
    const __hip_bfloat16* __restrict__ Web, __hip_bfloat16* __restrict__ Wt3,
    __hip_bfloat16* __restrict__ ballb) {
    __shared__ float WeS[16][193];
    const int lh = blockIdx.y, l = lh >> 2, hh = lh & 3;
    const int t = threadIdx.x;
    const int bf = *flag;
    for (int i = t; i < 16 * 192; i += 256) {
        int j = i / 192, c = i % 192;
        WeS[j][c] = (float)Web[(size_t)l * EDIM * DD + (size_t)j * DD + hh * CC + c];
    }
    __syncthreads();
    const int k = blockIdx.x * 64 + (t >> 2);
    const int j0 = (t & 3) * 4;
    float s0 = 0.f, s1 = 0.f, s2 = 0.f, s3 = 0.f;
    if (bf) {
        const short8* qp = (const short8*)((const __hip_bfloat16*)Wq +
            ((size_t)l * DD + k) * DD + hh * CC);
#pragma unroll 4
        for (int ch = 0; ch < 24; ch++) {
            short8 v = qp[ch];
#pragma unroll
            for (int u = 0; u < 8; u++) {
                float w = b2f(v[u]);
                int c = ch * 8 + u;
                s0 += w * WeS[j0 + 0][c]; s1 += w * WeS[j0 + 1][c];
                s2 += w * WeS[j0 + 2][c]; s3 += w * WeS[j0 + 3][c];
            }
        }
    } else {
        const float4* qp = (const float4*)((const float*)Wq +
            ((size_t)l * DD + k) * DD + hh * CC);
#pragma unroll 4
        for (int ch = 0; ch < 48; ch++) {
            float4 v = qp[ch];
            float wv[4] = {v.x, v.y, v.z, v.w};
#pragma unroll
            for (int u = 0; u < 4; u++) {
                float w = wv[u];
                int c = ch * 4 + u;
                s0 += w * WeS[j0 + 0][c]; s1 += w * WeS[j0 + 1][c];
                s2 += w * WeS[j0 + 2][c]; s3 += w * WeS[j0 + 3][c];
            }
        }
    }
    const size_t base = (size_t)l * NQ2 * DD;
    const int row = 3072 + hh * 16 + j0;
    Wt3[base + (size_t)(row + 0) * DD + k] = __float2bfloat16(s0);
    Wt3[base + (size_t)(row + 1) * DD + k] = __float2bfloat16(s1);
    Wt3[base + (size_t)(row + 2) * DD + k] = __float2bfloat16(s2);
    Wt3[base + (size_t)(row + 3) * DD + k] = __float2bfloat16(s3);
    const int prow = 3136 + hh * 16 + j0;
#pragma unroll
    for (int i = 0; i < 4; i++)
        Wt3[base + (size_t)(prow + i) * DD + k] = __float2bfloat16(0.0f);
    if (blockIdx.x == 0 && t < 4) {
        float b0 = 0.f, b1 = 0.f, b2 = 0.f, b3 = 0.f;
        for (int c = 0; c < CC; c++) {
            float w = (float)rd_any(bq, (long long)l * DD + hh * CC + c, bf);
            b0 += w * WeS[j0 + 0][c]; b1 += w * WeS[j0 + 1][c];
            b2 += w * WeS[j0 + 2][c]; b3 += w * WeS[j0 + 3][c];
        }
        ballb[l * NQ2 + 3072 + hh * 16 + j0 + 0] = __float2bfloat16(b0);
        ballb[l * NQ2 + 3072 + hh * 16 + j0 + 1] = __float2bfloat16(b1);
        ballb[l * NQ2 + 3072 + hh * 16 + j0 + 2] = __float2bfloat16(b2);
        ballb[l * NQ2 + 3072 + hh * 16 + j0 + 3] = __float2bfloat16(b3);
    }
}

// ---------------- CSR build (incoming edges per dst) ----------------

__global__ __launch_bounds__(256) void count_kernel(const int* ei, int* counts) {
    int e = blockIdx.x * 256 + threadIdx.x;
    if (e < EE) atomicAdd(&counts[ei[EE + e]], 1);
}

// scan also writes cursor (= exclusive prefix)
__global__ __launch_bounds__(256) void scan_kernel(const int* counts, int* rowptr,
                                                   int* cursor) {
    __shared__ int sdata[256];
    int t = threadIdx.x;
    int base = t * 40;
    int cnt = (base < NN) ? min(40, NN - base) : 0;
    int s = 0;
    for (int i = 0; i < cnt; i++) s += counts[base + i];
    sdata[t] = s;
    __syncthreads();
    for (int off = 1; off < 256; off <<= 1) {
        int add = (t >= off) ? sdata[t - off] : 0;
        __syncthreads();
        sdata[t] += add;
        __syncthreads();
    }
    int run = sdata[t] - s;  // exclusive prefix
    for (int i = 0; i < cnt; i++) {
        cursor[base + i] = run;
        run += counts[base + i];
        rowptr[base + i + 1] = run;
    }
    if (t == 0) rowptr[0] = 0;
}

__global__ __launch_bounds__(256) void fill_kernel(const int* ei, int* cursor,
                                                   int* eids, int* esrc) {
    int e = blockIdx.x * 256 + threadIdx.x;
    if (e < EE) {
        int d = ei[EE + e];
        int pos = atomicAdd(&cursor[d], 1);
        eids[pos] = e;
        esrc[pos] = ei[e];
    }
}

// ---------------- edge features (CSR-ordered, bf16) ----------------

__global__ __launch_bounds__(256) void ef_kernel(
    const int* __restrict__ eids,
    const __hip_bfloat16* __restrict__ eab, const __hip_bfloat16* __restrict__ relb,
    const __hip_bfloat16* __restrict__ Wedb, const __hip_bfloat16* __restrict__ bedb,
    __hip_bfloat16* __restrict__ efb) {
    int idx = blockIdx.x * 256 + threadIdx.x;
    if (idx >= EE * EDIM) return;
    int p = idx >> 4, j = idx & 15;
    int e = eids[p];
    int rid = (int)((float)eab[e * 2 + 0]);
    rid = min(max(rid, 0), NREL - 1);
    float w = (float)eab[e * 2 + 1];
    float s = (float)bedb[j];
#pragma unroll
    for (int i = 0; i < 15; i++)
        s += (float)relb[rid * 15 + i] * (float)Wedb[i * EDIM + j];
    s += w * (float)Wedb[15 * EDIM + j];
    efb[idx] = __float2bfloat16(s);
}

// ---------------- fused GEMM: C[NN,3200] = A[MP,768] @ Wt[3200,768]^T + bias ----

__global__ __launch_bounds__(256) void gemm_fused(
    const __hip_bfloat16* __restrict__ A, const __hip_bfloat16* __restrict__ Bt,
    const __hip_bfloat16* __restrict__ bias, __hip_bfloat16* __restrict__ C) {
    __shared__ __hip_bfloat16 As[128 * 32];   // 8 KB
    __shared__ __hip_bfloat16 Bs[128 * 32];   // 8 KB
    __shared__ __hip_bfloat16 stg[32 * 132];  // 8.25 KB, padded stride 132
    const int tid  = threadIdx.x;
    const int wid  = tid >> 6, lane = tid & 63;
    const int quad = lane >> 4, l15 = lane & 15;
    const int m0 = blockIdx.y * 128, n0 = blockIdx.x * 128;
    const int wm = wid >> 1, wn = wid & 1;
    floatx4 acc[4][4] = {};
    for (int k0 = 0; k0 < DD; k0 += 32) {
#pragma unroll
        for (int j = 0; j < 2; j++) {
            int c = j * 256 + tid;            // chunk index, 16B each
            int r = c >> 2, s = c & 3;
            int ks = s ^ ((r + (r >> 2)) & 3);   // XOR swizzle
            gload16(A + (size_t)(m0 + r) * DD + k0 + ks * 8, As + c * 8);
            gload16(Bt + (size_t)(n0 + r) * DD + k0 + ks * 8, Bs + c * 8);
        }
        __syncthreads();
        short8 a[4], b[4];
#pragma unroll
        for (int mt = 0; mt < 4; mt++) {
            int R = wm * 64 + mt * 16 + l15;
            int sw = quad ^ ((R + (R >> 2)) & 3);
            a[mt] = *(const short8*)(As + R * 32 + sw * 8);
        }
#pragma unroll
        for (int nt = 0; nt < 4; nt++) {
            int R = wn * 64 + nt * 16 + l15;
            int sw = quad ^ ((R + (R >> 2)) & 3);
            b[nt] = *(const short8*)(Bs + R * 32 + sw * 8);
        }
#pragma unroll
        for (int mt = 0; mt < 4; mt++)
#pragma unroll
            for (int nt = 0; nt < 4; nt++)
                acc[mt][nt] = __builtin_amdgcn_mfma_f32_16x16x32_bf16(a[mt], b[nt], acc[mt][nt], 0, 0, 0);
        __syncthreads();
    }
    float bv[4];
#pragma unroll
    for (int nt = 0; nt < 4; nt++) bv[nt] = (float)bias[n0 + wn * 64 + nt * 16 + l15];
    const int rr = tid >> 3, ccs = (tid & 7) * 16;
    const int grow = m0 + (rr >> 4) * 64 + (rr & 15);
    for (int mt = 0; mt < 4; mt++) {
#pragma unroll
        for (int nt = 0; nt < 4; nt++) {
            int col = wn * 64 + nt * 16 + l15;
#pragma unroll
            for (int r = 0; r < 4; r++) {
                int lr = wm * 16 + quad * 4 + r;
                stg[lr * 132 + col] = __float2bfloat16(acc[mt][nt][r] + bv[nt]);
            }
        }
        __syncthreads();
        int row = grow + mt * 16;
        if (row < NN) {
            const short8* sp = (const short8*)(stg + rr * 132 + ccs);
            short8 v0 = sp[0], v1 = sp[1];
            short8* dp = (short8*)(C + (size_t)row * NQ2 + n0 + ccs);
            dp[0] = v0; dp[1] = v1;
        }
        __syncthreads();
    }
}

// ---------------- attention ----------------
// qkvs row layout (stride 3200): [q(0) | k(768) | v(1536) | skip(2304) | Qe(3072)]

// TWO waves per node (grid 5000 blocks x 4 waves): wave half=0 handles heads
// {0,1} (channels 0..383), half=1 heads {2,3} (384..767). Lane owns 6 channels.
// Alpha reduced over 32-lane head groups (5 shfls). Online softmax + gather +
// S@We + skip + gelu, all in-wave.
__global__ __launch_bounds__(256) void node_attn(
    const int* __restrict__ rowptr, const int* __restrict__ esrc,
    const __hip_bfloat16* __restrict__ qkvs, const __hip_bfloat16* __restrict__ efb,
    const __hip_bfloat16* __restrict__ Wel, __hip_bfloat16* __restrict__ hb,
    int do_gelu) {
    const int wv = threadIdx.x >> 6, lane = threadIdx.x & 63;
    const int n = blockIdx.x * 2 + (wv >> 1);   // grid = 5000 blocks, exact
    const int half = wv & 1;
    const int cb = half * 384 + lane * 6;       // channel base within 768
    const int sj = lane & 15;
    const int hsel = lane & 32;                 // head-group base within wave
    const float qe_gate = ((lane & 16) == 0) ? 1.0f : 0.0f;
    const int s0 = rowptr[n], s1 = rowptr[n + 1];
    const short* qk = (const short*)qkvs;
    float q[6];
    {
        const short2* qp = (const short2*)(qk + (size_t)n * NQ2 + cb);
        short2 a = qp[0], b = qp[1], c = qp[2];
        q[0] = b2f(a.x); q[1] = b2f(a.y); q[2] = b2f(b.x);
        q[3] = b2f(b.y); q[4] = b2f(c.x); q[5] = b2f(c.y);
    }
    const float qe_l = b2f(qk[(size_t)n * NQ2 + 3072 + (half * 2 + (lane >> 5)) * 16 + sj]);
    float m = -INFINITY, lsum = 0.f, sacc = 0.f;
    float acc[6] = {};
    for (int p = s0; p < s1; p++) {
        int src = esrc[p];
        const short2* kp = (const short2*)(qk + (size_t)src * NQ2 + 768 + cb);
        const short2* vp = (const short2*)(qk + (size_t)src * NQ2 + 1536 + cb);
        short2 ka = kp[0], kb = kp[1], kc = kp[2];
        short2 va = vp[0], vb = vp[1], vc = vp[2];
        float efv = b2f(((const short*)efb)[(size_t)p * 16 + sj]);
        float part = qe_gate * qe_l * efv;
        part += q[0] * b2f(ka.x) + q[1] * b2f(ka.y) + q[2] * b2f(kb.x);
        part += q[3] * b2f(kb.y) + q[4] * b2f(kc.x) + q[5] * b2f(kc.y);
        part += __shfl_xor(part, 1); part += __shfl_xor(part, 2);
        part += __shfl_xor(part, 4); part += __shfl_xor(part, 8);
        part += __shfl_xor(part, 16);
        float a = part * SCALE;
        float nm = fmaxf(m, a);
        float sc = __expf(m - nm);
        float w  = __expf(a - nm);
        lsum = lsum * sc + w;
        m = nm;
        acc[0] = acc[0] * sc + w * b2f(va.x); acc[1] = acc[1] * sc + w * b2f(va.y);
        acc[2] = acc[2] * sc + w * b2f(vb.x); acc[3] = acc[3] * sc + w * b2f(vb.y);
        acc[4] = acc[4] * sc + w * b2f(vc.x); acc[5] = acc[5] * sc + w * b2f(vc.y);
        sacc = sacc * sc + w * efv;
    }
    float inv = 1.0f / (lsum + 1e-16f);
#pragma unroll
    for (int i = 0; i < 6; i++) acc[i] *= inv;
    float sS = sacc * inv;
    // skip connection
    {
        const short2* sp = (const short2*)(qk + (size_t)n * NQ2 + 2304 + cb);
        short2 a = sp[0], b = sp[1], c = sp[2];
        acc[0] += b2f(a.x); acc[1] += b2f(a.y); acc[2] += b2f(b.x);
        acc[3] += b2f(b.y); acc[4] += b2f(c.x); acc[5] += b2f(c.y);
    }
    // + S @ We (per-head 16-dim): S[h][j] broadcast via shfl from lane hsel+j
#pragma unroll
    for (int j = 0; j < 16; j++) {
        float sv = __shfl(sS, hsel + j);
        const short2* wp = (const short2*)(Wel + (size_t)j * DD + cb);
        short2 a = wp[0], b = wp[1], c = wp[2];
        acc[0] += sv * b2f(a.x); acc[1] += sv * b2f(a.y); acc[2] += sv * b2f(b.x);
        acc[3] += sv * b2f(b.y); acc[4] += sv * b2f(c.x); acc[5] += sv * b2f(c.y);
    }
    if (do_gelu) {
#pragma unroll
        for (int i = 0; i < 6; i++)
            acc[i] = 0.5f * acc[i] * (1.0f + erff(acc[i] * 0.70710678118654752f));
    }
    short2 o0, o1, o2;
    o0.x = f2b(acc[0]); o0.y = f2b(acc[1]);
    o1.x = f2b(acc[2]); o1.y = f2b(acc[3]);
    o2.x = f2b(acc[4]); o2.y = f2b(acc[5]);
    short2* hp = (short2*)(hb + (size_t)n * DD + cb);
    hp[0] = o0; hp[1] = o1; hp[2] = o2;
}

// ---------------- LN + mean pool ----------------

__global__ __launch_bounds__(256) void ln_pool(
    const __hip_bfloat16* __restrict__ hb, const __hip_bfloat16* __restrict__ g,
    const __hip_bfloat16* __restrict__ b, float* __restrict__ partial) {
    __shared__ float sbuf[4][768];
    int grp = blockIdx.x, t = threadIdx.x;
    int wid = t >> 6, lane = t & 63;
    float gv[12], bv[12], acc[12];
#pragma unroll
    for (int i = 0; i < 12; i++) {
        gv[i] = (float)g[lane + i * 64];
        bv[i] = (float)b[lane + i * 64];
        acc[i] = 0.f;
    }
    for (int r = wid; r < 25; r += 4) {
        const __hip_bfloat16* row = hb + (size_t)(grp * 25 + r) * DD;
        float x[12];
        float s = 0.f, q = 0.f;
#pragma unroll
        for (int i = 0; i < 12; i++) {
            x[i] = (float)row[lane + i * 64];
            s += x[i]; q += x[i] * x[i];
        }
#pragma unroll
        for (int m = 32; m > 0; m >>= 1) {
            s += __shfl_xor(s, m); q += __shfl_xor(q, m);
        }
        float mu = s * (1.0f / 768.0f);
        float ms = q * (1.0f / 768.0f);
        float inv = 1.0f / sqrtf(ms - mu * mu + 1e-5f);
#pragma unroll
        for (int i = 0; i < 12; i++)
            acc[i] += (x[i] - mu) * inv * gv[i] + bv[i];
    }
#pragma unroll
    for (int i = 0; i < 12; i++) sbuf[wid][lane + i * 64] = acc[i];
    __syncthreads();
#pragma unroll
    for (int j = 0; j < 3; j++) {
        int col = t + j * 256;
        partial[(size_t)grp * DD + col] =
            sbuf[0][col] + sbuf[1][col] + sbuf[2][col] + sbuf[3][col];
    }
}

// final pool: sum all 400 partials per column, store output
__global__ __launch_bounds__(256) void pool_final(
    const float* __restrict__ partial, void* __restrict__ out,
    const int* __restrict__ flag) {
    int dd = blockIdx.x * 256 + threadIdx.x;
    if (dd >= DD) return;
    float s = 0.f;
    for (int g2 = 0; g2 < 400; g2++) s += partial[(size_t)g2 * DD + dd];
    s *= (1.0f / 10000.0f);
    if (*flag) ((__hip_bfloat16*)out)[dd] = __float2bfloat16(s);
    else ((float*)out)[dd] = s;
}

// ---------------- launch ----------------

extern "C" void kernel_launch(void* const* d_in, const int* in_sizes, int n_in,
                              void* d_out, int out_size, void* d_ws, size_t ws_size,
                              hipStream_t stream) {
    const void* x         = d_in[0];
    const void* edge_attr = d_in[1];
    const int*  ei        = (const int*)d_in[2];
    const void* rel_emb   = d_in[3];
    const void* W_edge    = d_in[4];
    const void* b_edge    = d_in[5];
    const void* Wk        = d_in[6];
    const void* bk        = d_in[7];
    const void* Wq        = d_in[8];
    const void* bq        = d_in[9];
    const void* Wv        = d_in[10];
    const void* bv        = d_in[11];
    const void* We        = d_in[12];
    const void* Wskip     = d_in[13];
    const void* bskip     = d_in[14];
    const void* ln_g      = d_in[15];
    const void* ln_b      = d_in[16];

    char* ws = (char*)d_ws;
    // ---- workspace layout (~100.2 MB total) ----
    int*   flag    = (int*)(ws + 0);
    int*   counts  = (int*)(ws + 256);          // 40,000
    int*   rowptr  = (int*)(ws + 40448);        // 40,004
    int*   cursor  = (int*)(ws + 80640);        // 40,000
    int*   eids    = (int*)(ws + 120832);       // 400,000
    int*   esrc    = (int*)(ws + 520960);       // 400,000
    __hip_bfloat16* efb = (__hip_bfloat16*)(ws + 920960);   // 3,200,000 (CSR-ordered)
    float* partial = (float*)(ws + 4120960);    // 1,228,800
    __hip_bfloat16* eab   = (__hip_bfloat16*)(ws + 5398912);  // 400,000
    __hip_bfloat16* relb  = (__hip_bfloat16*)(ws + 5799296);  // 300
    __hip_bfloat16* Wedb  = (__hip_bfloat16*)(ws + 5799680);  // 512
    __hip_bfloat16* bedb  = (__hip_bfloat16*)(ws + 5800192);  // 32
    __hip_bfloat16* ballb = (__hip_bfloat16*)(ws + 5800320);  // 19,200 (3*3200)
    __hip_bfloat16* lngb  = (__hip_bfloat16*)(ws + 5819520);  // 1,536
    __hip_bfloat16* lnbb  = (__hip_bfloat16*)(ws + 5821056);  // 1,536
    __hip_bfloat16* Web   = (__hip_bfloat16*)(ws + 5822592);  // 73,728
    __hip_bfloat16* hb    = (__hip_bfloat16*)(ws + 5896320);  // 15,532,032 (MP*768)
    __hip_bfloat16* Wt3   = (__hip_bfloat16*)(ws + 21428352); // 14,745,600 (3*3200*768)
    __hip_bfloat16* qkvs  = (__hip_bfloat16*)(ws + 36173952); // 64,000,000 -> 100,173,952

    dim3 blk(256);

    detect_zero<<<dim3(40), blk, 0, stream>>>(edge_attr, flag, counts);

    {
        long long tot = (long long)NN * DD + 3LL * EDIM * DD + (long long)(MP - NN) * DD;
        cvt_big<<<dim3((unsigned)((tot + 255) / 256)), blk, 0, stream>>>(x, We, flag, hb, Web);
    }
    {
        long long tot = 2LL * EE + NREL * (EDIM - 1) + EDIM * EDIM + EDIM
                        + 3LL * NQ2 + 2LL * DD;
        cvt_small<<<dim3((unsigned)((tot + 255) / 256)), blk, 0, stream>>>(
            edge_attr, rel_emb, W_edge, b_edge, bk, bq, bv, bskip, ln_g, ln_b,
            flag, eab, relb, Wedb, bedb, ballb, lngb, lnbb);
    }
    wt_all<<<dim3(576, 12), blk, 0, stream>>>(Wq, Wk, Wv, Wskip, flag, Wt3);
    mq_kernel<<<dim3(12, 12), blk, 0, stream>>>(Wq, bq, flag, Web, Wt3, ballb);

    // CSR build
    count_kernel<<<dim3((EE + 255) / 256), blk, 0, stream>>>(ei, counts);
    scan_kernel<<<dim3(1), blk, 0, stream>>>(counts, rowptr, cursor);
    fill_kernel<<<dim3((EE + 255) / 256), blk, 0, stream>>>(ei, cursor, eids, esrc);

    ef_kernel<<<dim3((EE * EDIM) / 256), blk, 0, stream>>>(eids, eab, relb, Wedb, bedb, efb);

    for (int l = 0; l < 3; l++) {
        const __hip_bfloat16* We_l = Web + (size_t)l * EDIM * DD;
        gemm_fused<<<dim3(NQ2 / 128, MP / 128), blk, 0, stream>>>(
            hb, Wt3 + (size_t)l * NQ2 * DD, ballb + (size_t)l * NQ2, qkvs);
        node_attn<<<dim3(NN / 2), blk, 0, stream>>>(rowptr, esrc, qkvs, efb,
                                                    We_l, hb, (l < 2) ? 1 : 0);
    }

    ln_pool<<<dim3(400), blk, 0, stream>>>(hb, lngb, lnbb, partial);
    pool_final<<<dim3(3), blk, 0, stream>>>(partial, d_out, flag);
}